// Round 5
// baseline (129.337 us; speedup 1.0000x reference)
//
#include <hip/hip_runtime.h>

#define BB 8
#define SS 2048
#define HH 128
#define NHH 4
#define DHH 32

typedef _Float16 f16;
typedef f16 f16x4 __attribute__((ext_vector_type(4)));
typedef f16 f16x8 __attribute__((ext_vector_type(8)));
typedef float f32x4 __attribute__((ext_vector_type(4)));

__device__ __forceinline__ f16x8 cat(f16x4 a, f16x4 b) {
  return (f16x8){a[0], a[1], a[2], a[3], b[0], b[1], b[2], b[3]};
}

// hardware transpose read (R2/R3-proven): on a contiguous [16 rows][16 cols] f16
// panel, tr_read(panel + lane*4) gives lane(lg,lm) elem j = panel[row 4*lg+j][col lm].
// CALLER MUST insert s_waitcnt lgkmcnt(0) + sched_barrier(0) before using the result
// (rule #18: compiler does not track the DS op issued inside the asm).
__device__ __forceinline__ f16x4 tr_read(const f16* p) {
  f16x4 d;
  asm volatile("ds_read_b64_tr_b16 %0, %1"
               : "=v"(d)
               : "v"((__attribute__((address_space(3))) const f16*)p)
               : "memory");
  return d;
}

// ---------------- LayerNorm -> n1 (row-major f16) + n1T ([b][d][s] f16) ------
// block = 256 thr, 16 rows; 16-lane group per row, 8 elems/lane
__global__ __launch_bounds__(256) void ln_kernel(const float* __restrict__ x,
                                                 const float* __restrict__ ga,
                                                 const float* __restrict__ gb,
                                                 f16* __restrict__ n1,
                                                 f16* __restrict__ n1T) {
  const int tid = threadIdx.x;
  const int wave = tid >> 6, lane = tid & 63;
  const int grp = lane >> 4, lm = lane & 15;
  const int r = wave * 4 + grp;  // local row 0..15
  const size_t row = (size_t)blockIdx.x * 16 + r;

  __shared__ __align__(16) f16 Tl[8 * 520];  // 8 panels [16s][16d], pad 8

  const float* xr = x + row * HH + lm * 8;
  float4 v0 = *(const float4*)(xr);
  float4 v1 = *(const float4*)(xr + 4);
  float xv[8] = {v0.x, v0.y, v0.z, v0.w, v1.x, v1.y, v1.z, v1.w};
  float sum = 0.f, sq = 0.f;
#pragma unroll
  for (int j = 0; j < 8; ++j) { sum += xv[j]; sq += xv[j] * xv[j]; }
#pragma unroll
  for (int m = 1; m < 16; m <<= 1) {
    sum += __shfl_xor(sum, m);
    sq += __shfl_xor(sq, m);
  }
  float mean = sum * (1.0f / HH);
  float var = fmaxf((sq - (float)HH * mean * mean) * (1.0f / (HH - 1)), 0.0f);
  float inv = 1.0f / (sqrtf(var) + 1e-6f);

  float4 a0 = *(const float4*)(ga + lm * 8);
  float4 a1 = *(const float4*)(ga + lm * 8 + 4);
  float4 b0 = *(const float4*)(gb + lm * 8);
  float4 b1 = *(const float4*)(gb + lm * 8 + 4);
  float av[8] = {a0.x, a0.y, a0.z, a0.w, a1.x, a1.y, a1.z, a1.w};
  float bv[8] = {b0.x, b0.y, b0.z, b0.w, b1.x, b1.y, b1.z, b1.w};
  f16x8 w;
#pragma unroll
  for (int j = 0; j < 8; ++j) w[j] = (f16)(av[j] * (xv[j] - mean) * inv + bv[j]);

  *(f16x8*)(n1 + row * HH + lm * 8) = w;
  // panel p = lm>>1 holds d-cols [p*16, p*16+16); this lane's 8 d start at (lm&1)*8
  *(f16x8*)(&Tl[(lm >> 1) * 520 + r * 16 + (lm & 1) * 8]) = w;
  __syncthreads();

  const int bb = (int)((blockIdx.x * 16) >> 11);
  const int sb = (blockIdx.x * 16) & 2047;
  const int p0 = wave * 2;
  // issue BOTH transpose reads, then wait, then use (rule #18)
  f16x4 tv0 = tr_read(&Tl[p0 * 520] + lane * 4);        // elem j = panel[s=4lg+j][d=lm]
  f16x4 tv1 = tr_read(&Tl[(p0 + 1) * 520] + lane * 4);
  asm volatile("s_waitcnt lgkmcnt(0)" ::: "memory");
  __builtin_amdgcn_sched_barrier(0);
  int d0 = p0 * 16 + lm;
  *(f16x4*)(n1T + ((size_t)bb * HH + d0) * SS + sb + (lane >> 4) * 4) = tv0;
  int d1 = (p0 + 1) * 16 + lm;
  *(f16x4*)(n1T + ((size_t)bb * HH + d1) * SS + sb + (lane >> 4) * 4) = tv1;
}

// ---------------- prep: weights->f16, mask->exp2 bias ----------------
__global__ __launch_bounds__(256) void prep_kernel(const float* __restrict__ Wl,
                                                   const float* __restrict__ W1,
                                                   const int* __restrict__ mask,
                                                   f16* __restrict__ Wlf,
                                                   f16* __restrict__ W1f,
                                                   float* __restrict__ mb) {
  int g = blockIdx.x * 256 + threadIdx.x;
  if (g < 4096) {
    float4 w = ((const float4*)Wl)[g];
    f16x4 o = {(f16)w.x, (f16)w.y, (f16)w.z, (f16)w.w};
    ((f16x4*)Wlf)[g] = o;
  } else if (g < 8192) {
    float4 w = ((const float4*)W1)[g - 4096];
    f16x4 o = {(f16)w.x, (f16)w.y, (f16)w.z, (f16)w.w};
    ((f16x4*)W1f)[g - 4096] = o;
  } else {
    int4 m = ((const int4*)mask)[g - 8192];
    float4 o;
    o.x = m.x ? -5.7707801636f : -1.5e9f;  // (-4)*log2e  or  -inf-ish
    o.y = m.y ? -5.7707801636f : -1.5e9f;
    o.z = m.z ? -5.7707801636f : -1.5e9f;
    o.w = m.w ? -5.7707801636f : -1.5e9f;
    ((float4*)mb)[g - 8192] = o;
  }
}

// ---------------- attention: LDS-free, all operands from L2 ----------------
// grid = B*NH*(S/128) = 512; block 256 = 4 waves; wave = 32 queries (2 frags)
__global__ __launch_bounds__(256) void attn_kernel(const f16* __restrict__ n1,
                                                   const f16* __restrict__ n1T,
                                                   const float* __restrict__ mbias,
                                                   const float* __restrict__ scalew,
                                                   f16* __restrict__ hatt) {
  const int tid = threadIdx.x;
  const int qb = blockIdx.x & 15;
  const int h = (blockIdx.x >> 4) & 3;
  const int b = blockIdx.x >> 6;
  const int wave = tid >> 6, lane = tid & 63;
  const int lg = lane >> 4, lm = lane & 15;

  const f16* __restrict__ nb = n1 + (size_t)b * SS * HH + h * DHH;
  const f16* __restrict__ ntb = n1T + ((size_t)b * HH + h * DHH) * SS;
  const float* __restrict__ mbb = mbias + b * SS;

  const int q0 = qb * 128 + wave * 32 + lm;
  f16x8 qf[2];
  float sc2[2];
#pragma unroll
  for (int qt = 0; qt < 2; ++qt) {
    int q = q0 + qt * 16;
    qf[qt] = *(const f16x8*)(nb + (size_t)q * HH + lg * 8);
    sc2[qt] = scalew[h * SS + q] * 0.2550680718664f;  // (1/sqrt32)*log2e
  }

  const f16* kfp = nb + (size_t)lm * HH + lg * 8;        // + key*HH
  const f16* vbase = ntb + (size_t)lm * SS + lg * 4;     // + dh*16*SS + s*32 (+16 hi) + k0

  const f32x4 zero = {0.f, 0.f, 0.f, 0.f};
  f32x4 acc[2][2] = {{zero, zero}, {zero, zero}};  // [qt][dh]
  float lsum[2] = {0.f, 0.f};

  f16x8 kf[4];
  f16x4 vl[4], vh[4];  // index = dh*2 + s
#pragma unroll
  for (int t = 0; t < 4; ++t) kf[t] = *(const f16x8*)(kfp + (size_t)(t * 16) * HH);
#pragma unroll
  for (int i = 0; i < 4; ++i) {
    const f16* p = vbase + (size_t)(i >> 1) * 16 * SS + (i & 1) * 32;
    vl[i] = *(const f16x4*)(p);
    vh[i] = *(const f16x4*)(p + 16);
  }

  for (int c = 0; c < 32; ++c) {
    const int k0 = c * 64;
    f16x8 kn[4];
    f16x4 vln[4], vhn[4];
    if (c < 31) {  // prefetch next chunk into regs
#pragma unroll
      for (int t = 0; t < 4; ++t)
        kn[t] = *(const f16x8*)(kfp + (size_t)(k0 + 64 + t * 16) * HH);
#pragma unroll
      for (int i = 0; i < 4; ++i) {
        const f16* p = vbase + (size_t)(i >> 1) * 16 * SS + (i & 1) * 32 + k0 + 64;
        vln[i] = *(const f16x4*)(p);
        vhn[i] = *(const f16x4*)(p + 16);
      }
    }
    float4 mv[4];
#pragma unroll
    for (int t = 0; t < 4; ++t) mv[t] = *(const float4*)(mbb + k0 + t * 16 + lg * 4);

    f16x8 pf[2][2];
#pragma unroll
    for (int qt = 0; qt < 2; ++qt) {
#pragma unroll
      for (int t = 0; t < 4; ++t) {
        f32x4 st = __builtin_amdgcn_mfma_f32_16x16x32_f16(kf[t], qf[qt], zero, 0, 0, 0);
        const float* mp = &mv[t].x;
#pragma unroll
        for (int r = 0; r < 4; ++r) {
          float pe = __builtin_amdgcn_exp2f(st[r] * sc2[qt] + mp[r]);
          lsum[qt] += pe;
          pf[qt][t >> 1][(t & 1) * 4 + r] = (f16)pe;
        }
      }
    }
#pragma unroll
    for (int s = 0; s < 2; ++s) {
      f16x8 vf0 = cat(vl[s], vh[s]);
      f16x8 vf1 = cat(vl[2 + s], vh[2 + s]);
#pragma unroll
      for (int qt = 0; qt < 2; ++qt) {
        acc[qt][0] = __builtin_amdgcn_mfma_f32_16x16x32_f16(vf0, pf[qt][s], acc[qt][0], 0, 0, 0);
        acc[qt][1] = __builtin_amdgcn_mfma_f32_16x16x32_f16(vf1, pf[qt][s], acc[qt][1], 0, 0, 0);
      }
    }
    if (c < 31) {
#pragma unroll
      for (int t = 0; t < 4; ++t) kf[t] = kn[t];
#pragma unroll
      for (int i = 0; i < 4; ++i) { vl[i] = vln[i]; vh[i] = vhn[i]; }
    }
  }

#pragma unroll
  for (int qt = 0; qt < 2; ++qt) {
    float ls = lsum[qt];
    ls += __shfl_xor(ls, 16);
    ls += __shfl_xor(ls, 32);
    float inv = 1.0f / ls;
    int q = q0 + qt * 16;
    f16* op = hatt + (size_t)(b * SS + q) * HH + h * DHH;
    f16x4 o0 = {(f16)(acc[qt][0][0] * inv), (f16)(acc[qt][0][1] * inv),
                (f16)(acc[qt][0][2] * inv), (f16)(acc[qt][0][3] * inv)};
    f16x4 o1 = {(f16)(acc[qt][1][0] * inv), (f16)(acc[qt][1][1] * inv),
                (f16)(acc[qt][1][2] * inv), (f16)(acc[qt][1][3] * inv)};
    *(f16x4*)(op + lg * 4) = o0;
    *(f16x4*)(op + 16 + lg * 4) = o1;
  }
}

// ------- fused: out = resid + X@Wl^T + bl; n2 = LN2(out); out += gelu(fs*(n2@W1^T+b1))
// block 128 = 2 waves; 16 rows x 128 cols; grid = rows/16 = 1024
__global__ __launch_bounds__(128) void mlp_kernel(const f16* __restrict__ X,
                                                  const f16* __restrict__ Wlf,
                                                  const float* __restrict__ bl,
                                                  const float* __restrict__ resid,
                                                  const float* __restrict__ ln2a,
                                                  const float* __restrict__ ln2b,
                                                  const f16* __restrict__ W1f,
                                                  const float* __restrict__ b1,
                                                  const float* __restrict__ fscale,
                                                  float* __restrict__ out) {
  const int tid = threadIdx.x;
  const int wave = tid >> 6, lane = tid & 63;
  const int lg = lane >> 4, lm = lane & 15;
  const int row = blockIdx.x * 16 + lm;
  const int nc0 = wave * 64;

  __shared__ __align__(16) f16 n2t[16][136];
  __shared__ float red[2][16][2];

  f32x4 acc[4] = {};
  const f16* xr = X + (size_t)row * HH;
#pragma unroll
  for (int ks = 0; ks < 4; ++ks) {
    f16x8 bf = *(const f16x8*)(xr + ks * 32 + lg * 8);
#pragma unroll
    for (int nt = 0; nt < 4; ++nt) {
      f16x8 af = *(const f16x8*)(Wlf + (size_t)(nc0 + nt * 16 + lm) * HH + ks * 32 + lg * 8);
      acc[nt] = __builtin_amdgcn_mfma_f32_16x16x32_f16(af, bf, acc[nt], 0, 0, 0);
    }
  }
  float sum = 0.f, sq = 0.f;
  f32x4 o[4];
#pragma unroll
  for (int nt = 0; nt < 4; ++nt) {
    int n = nc0 + nt * 16 + lg * 4;
    float4 rv = *(const float4*)(resid + (size_t)row * HH + n);
    float4 bv = *(const float4*)(bl + n);
    f32x4 v = acc[nt];
    v[0] += rv.x + bv.x; v[1] += rv.y + bv.y;
    v[2] += rv.z + bv.z; v[3] += rv.w + bv.w;
    o[nt] = v;
    sum += v[0] + v[1] + v[2] + v[3];
    sq += v[0] * v[0] + v[1] * v[1] + v[2] * v[2] + v[3] * v[3];
  }
  sum += __shfl_xor(sum, 16); sum += __shfl_xor(sum, 32);
  sq += __shfl_xor(sq, 16);  sq += __shfl_xor(sq, 32);
  if (lane < 16) { red[wave][lm][0] = sum; red[wave][lm][1] = sq; }
  __syncthreads();
  float ts = red[0][lm][0] + red[1][lm][0];
  float tq = red[0][lm][1] + red[1][lm][1];
  float mean = ts * (1.0f / HH);
  float var = fmaxf((tq - (float)HH * mean * mean) * (1.0f / (HH - 1)), 0.0f);
  float inv = 1.0f / (sqrtf(var) + 1e-6f);
#pragma unroll
  for (int nt = 0; nt < 4; ++nt) {
    int n = nc0 + nt * 16 + lg * 4;
    float4 av = *(const float4*)(ln2a + n);
    float4 b2 = *(const float4*)(ln2b + n);
    f16x4 w;
    w[0] = (f16)(av.x * (o[nt][0] - mean) * inv + b2.x);
    w[1] = (f16)(av.y * (o[nt][1] - mean) * inv + b2.y);
    w[2] = (f16)(av.z * (o[nt][2] - mean) * inv + b2.z);
    w[3] = (f16)(av.w * (o[nt][3] - mean) * inv + b2.w);
    *(f16x4*)(&n2t[lm][n]) = w;
  }
  __syncthreads();

  f32x4 fa[4] = {};
#pragma unroll
  for (int ks = 0; ks < 4; ++ks) {
    f16x8 bf = *(const f16x8*)(&n2t[lm][ks * 32 + lg * 8]);
#pragma unroll
    for (int nt = 0; nt < 4; ++nt) {
      f16x8 af = *(const f16x8*)(W1f + (size_t)(nc0 + nt * 16 + lm) * HH + ks * 32 + lg * 8);
      fa[nt] = __builtin_amdgcn_mfma_f32_16x16x32_f16(af, bf, fa[nt], 0, 0, 0);
    }
  }
  float fs = fscale[row & (SS - 1)];
#pragma unroll
  for (int nt = 0; nt < 4; ++nt) {
    int n = nc0 + nt * 16 + lg * 4;
    float4 bv = *(const float4*)(b1 + n);
    const float* bp = &bv.x;
#pragma unroll
    for (int e = 0; e < 4; ++e) {
      float hf = fs * (fa[nt][e] + bp[e]);
      float u = 0.7978845608028654f * hf * (1.0f + 0.044715f * hf * hf);
      float ex = __builtin_amdgcn_exp2f(u * 2.8853900817779268f);  // exp(2u)
      float t = 1.0f - 2.0f / (ex + 1.0f);
      o[nt][e] += 0.5f * hf * (1.0f + t);
    }
    *(f32x4*)(out + (size_t)row * HH + n) = o[nt];
  }
}

extern "C" void kernel_launch(void* const* d_in, const int* in_sizes, int n_in,
                              void* d_out, int out_size, void* d_ws, size_t ws_size,
                              hipStream_t stream) {
  const float* hidden = (const float*)d_in[0];
  const int* mask = (const int*)d_in[1];
  const float* scalew = (const float*)d_in[2];
  const float* Wl = (const float*)d_in[3];
  const float* bl = (const float*)d_in[4];
  const float* W1 = (const float*)d_in[5];
  const float* b1 = (const float*)d_in[6];
  const float* fscale = (const float*)d_in[7];
  const float* ln1a = (const float*)d_in[8];
  const float* ln1b = (const float*)d_in[9];
  const float* ln2a = (const float*)d_in[10];
  const float* ln2b = (const float*)d_in[11];
  float* out = (float*)d_out;

  const size_t NE = (size_t)BB * SS * HH;  // 2M elements
  f16* n1 = (f16*)d_ws;
  f16* n1T = n1 + NE;
  f16* hattf = n1T + NE;
  f16* Wlf = hattf + NE;
  f16* W1f = Wlf + HH * HH;
  float* mb = (float*)(W1f + HH * HH);

  const int rows = BB * SS;
  prep_kernel<<<48, 256, 0, stream>>>(Wl, W1, mask, Wlf, W1f, mb);
  ln_kernel<<<rows / 16, 256, 0, stream>>>(hidden, ln1a, ln1b, n1, n1T);
  attn_kernel<<<BB * NHH * (SS / 128), 256, 0, stream>>>(n1, n1T, mb, scalew, hattf);
  mlp_kernel<<<rows / 16, 128, 0, stream>>>(hattf, Wlf, bl, hidden, ln2a, ln2b,
                                            W1f, b1, fscale, out);
}

// Round 6
// 64.764 us; speedup vs baseline: 1.9970x; 1.9970x over previous
//
#include <hip/hip_runtime.h>

#define BB 8
#define SS 2048
#define HH 128
#define NHH 4
#define DHH 32

typedef _Float16 f16;
typedef f16 f16x4 __attribute__((ext_vector_type(4)));
typedef f16 f16x8 __attribute__((ext_vector_type(8)));
typedef float f32x4 __attribute__((ext_vector_type(4)));

__device__ __forceinline__ f16x8 cat(f16x4 a, f16x4 b) {
  return (f16x8){a[0], a[1], a[2], a[3], b[0], b[1], b[2], b[3]};
}

// hardware transpose read (R2/R3-proven). CALLER MUST wait lgkmcnt(0) +
// sched_barrier(0) before using the result (rule #18).
__device__ __forceinline__ f16x4 tr_read(const f16* p) {
  f16x4 d;
  asm volatile("ds_read_b64_tr_b16 %0, %1"
               : "=v"(d)
               : "v"((__attribute__((address_space(3))) const f16*)p)
               : "memory");
  return d;
}

// ---------------- LayerNorm -> n1 (row-major f16) + n1T ([b][d][s] f16) ------
__global__ __launch_bounds__(256) void ln_kernel(const float* __restrict__ x,
                                                 const float* __restrict__ ga,
                                                 const float* __restrict__ gb,
                                                 f16* __restrict__ n1,
                                                 f16* __restrict__ n1T) {
  const int tid = threadIdx.x;
  const int wave = tid >> 6, lane = tid & 63;
  const int grp = lane >> 4, lm = lane & 15;
  const int r = wave * 4 + grp;  // local row 0..15
  const size_t row = (size_t)blockIdx.x * 16 + r;

  __shared__ __align__(16) f16 Tl[8 * 520];  // 8 panels [16s][16d], pad 8

  const float* xr = x + row * HH + lm * 8;
  float4 v0 = *(const float4*)(xr);
  float4 v1 = *(const float4*)(xr + 4);
  float xv[8] = {v0.x, v0.y, v0.z, v0.w, v1.x, v1.y, v1.z, v1.w};
  float sum = 0.f, sq = 0.f;
#pragma unroll
  for (int j = 0; j < 8; ++j) { sum += xv[j]; sq += xv[j] * xv[j]; }
#pragma unroll
  for (int m = 1; m < 16; m <<= 1) {
    sum += __shfl_xor(sum, m);
    sq += __shfl_xor(sq, m);
  }
  float mean = sum * (1.0f / HH);
  float var = fmaxf((sq - (float)HH * mean * mean) * (1.0f / (HH - 1)), 0.0f);
  float inv = 1.0f / (sqrtf(var) + 1e-6f);

  float4 a0 = *(const float4*)(ga + lm * 8);
  float4 a1 = *(const float4*)(ga + lm * 8 + 4);
  float4 b0 = *(const float4*)(gb + lm * 8);
  float4 b1 = *(const float4*)(gb + lm * 8 + 4);
  float av[8] = {a0.x, a0.y, a0.z, a0.w, a1.x, a1.y, a1.z, a1.w};
  float bv[8] = {b0.x, b0.y, b0.z, b0.w, b1.x, b1.y, b1.z, b1.w};
  f16x8 w;
#pragma unroll
  for (int j = 0; j < 8; ++j) w[j] = (f16)(av[j] * (xv[j] - mean) * inv + bv[j]);

  *(f16x8*)(n1 + row * HH + lm * 8) = w;
  *(f16x8*)(&Tl[(lm >> 1) * 520 + r * 16 + (lm & 1) * 8]) = w;
  __syncthreads();

  const int bb = (int)((blockIdx.x * 16) >> 11);
  const int sb = (blockIdx.x * 16) & 2047;
  const int p0 = wave * 2;
  f16x4 tv0 = tr_read(&Tl[p0 * 520] + lane * 4);
  f16x4 tv1 = tr_read(&Tl[(p0 + 1) * 520] + lane * 4);
  asm volatile("s_waitcnt lgkmcnt(0)" ::: "memory");
  __builtin_amdgcn_sched_barrier(0);
  int d0 = p0 * 16 + lm;
  *(f16x4*)(n1T + ((size_t)bb * HH + d0) * SS + sb + (lane >> 4) * 4) = tv0;
  int d1 = (p0 + 1) * 16 + lm;
  *(f16x4*)(n1T + ((size_t)bb * HH + d1) * SS + sb + (lane >> 4) * 4) = tv1;
}

// ---------------- prep: weights->f16, mask->exp2 bias ----------------
__global__ __launch_bounds__(256) void prep_kernel(const float* __restrict__ Wl,
                                                   const float* __restrict__ W1,
                                                   const int* __restrict__ mask,
                                                   f16* __restrict__ Wlf,
                                                   f16* __restrict__ W1f,
                                                   float* __restrict__ mb) {
  int g = blockIdx.x * 256 + threadIdx.x;
  if (g < 4096) {
    float4 w = ((const float4*)Wl)[g];
    f16x4 o = {(f16)w.x, (f16)w.y, (f16)w.z, (f16)w.w};
    ((f16x4*)Wlf)[g] = o;
  } else if (g < 8192) {
    float4 w = ((const float4*)W1)[g - 4096];
    f16x4 o = {(f16)w.x, (f16)w.y, (f16)w.z, (f16)w.w};
    ((f16x4*)W1f)[g - 4096] = o;
  } else {
    int4 m = ((const int4*)mask)[g - 8192];
    float4 o;
    o.x = m.x ? -5.7707801636f : -1.5e9f;  // (-4)*log2e  or  -inf-ish
    o.y = m.y ? -5.7707801636f : -1.5e9f;
    o.z = m.z ? -5.7707801636f : -1.5e9f;
    o.w = m.w ? -5.7707801636f : -1.5e9f;
    ((float4*)mb)[g - 8192] = o;
  }
}

// ------- attention: shared double-buffered LDS tiles, 32 q/wave --------------
// grid = B*NH*(S/128) = 512; block 256 = 4 waves; chunk = 64 keys
__global__ __launch_bounds__(256, 2) void attn_kernel(const f16* __restrict__ n1,
                                                      const f16* __restrict__ n1T,
                                                      const float* __restrict__ mbias,
                                                      const float* __restrict__ scalew,
                                                      f16* __restrict__ hatt) {
  const int tid = threadIdx.x;
  const int qb = blockIdx.x & 15;
  const int h = (blockIdx.x >> 4) & 3;
  const int b = blockIdx.x >> 6;
  const int wave = tid >> 6, lane = tid & 63;
  const int lg = lane >> 4, lm = lane & 15;

  __shared__ __align__(16) f16 Kt[2][64][40];  // key-major, 80B stride
  __shared__ __align__(16) f16 Vt[2][32][72];  // d-major, 144B stride

  const f16* __restrict__ nb = n1 + (size_t)b * SS * HH + h * DHH;
  const f16* __restrict__ ntb = n1T + ((size_t)b * HH + h * DHH) * SS;
  const float* __restrict__ mbb = mbias + b * SS;

  const int q0 = qb * 128 + wave * 32 + lm;
  f16x8 qf[2];
  float sc2[2];
#pragma unroll
  for (int qt = 0; qt < 2; ++qt) {
    int q = q0 + qt * 16;
    qf[qt] = *(const f16x8*)(nb + (size_t)q * HH + lg * 8);
    sc2[qt] = scalew[h * SS + q] * 0.2550680718664f;  // (1/sqrt32)*log2e
  }

  // staging: K: thread -> key tid>>2, 16B part tid&3 ; V: d tid>>3, part tid&7
  const int sk = tid >> 2, skp = tid & 3;
  const int sd = tid >> 3, sdp = tid & 7;
  const f16* gK = nb + (size_t)sk * HH + skp * 8;
  const f16* gV = ntb + (size_t)sd * SS + sdp * 8;

  const f32x4 zero = {0.f, 0.f, 0.f, 0.f};
  f32x4 acc[2][2] = {{zero, zero}, {zero, zero}};  // [qt][dh]
  f32x4 lacc[2] = {zero, zero};
  const f16x8 ones = {(f16)1, (f16)1, (f16)1, (f16)1, (f16)1, (f16)1, (f16)1, (f16)1};

  f16x8 kreg = *(const f16x8*)(gK);
  f16x8 vreg = *(const f16x8*)(gV);
  *(f16x8*)(&Kt[0][sk][skp * 8]) = kreg;
  *(f16x8*)(&Vt[0][sd][sdp * 8]) = vreg;
  __syncthreads();

  for (int c = 0; c < 32; ++c) {
    const int buf = c & 1;
    const int k0 = c * 64;
    if (c < 31) {  // issue next chunk's global loads early
      kreg = *(const f16x8*)(gK + (size_t)(k0 + 64) * HH);
      vreg = *(const f16x8*)(gV + k0 + 64);
    }
    float4 mv[4];
#pragma unroll
    for (int t = 0; t < 4; ++t) mv[t] = *(const float4*)(mbb + k0 + t * 16 + lg * 4);

    f16x8 kf[4];
#pragma unroll
    for (int t = 0; t < 4; ++t) kf[t] = *(const f16x8*)(&Kt[buf][t * 16 + lm][lg * 8]);

    f16x8 pf[2][2];
#pragma unroll
    for (int qt = 0; qt < 2; ++qt) {
#pragma unroll
      for (int t = 0; t < 4; ++t) {
        f32x4 st = __builtin_amdgcn_mfma_f32_16x16x32_f16(kf[t], qf[qt], zero, 0, 0, 0);
        const float* mp = &mv[t].x;
#pragma unroll
        for (int r = 0; r < 4; ++r) {
          float pe = __builtin_amdgcn_exp2f(st[r] * sc2[qt] + mp[r]);
          pf[qt][t >> 1][(t & 1) * 4 + r] = (f16)pe;
        }
      }
    }
    // denominator on the matrix pipe: lacc += 1^T * P  (every lane gets full sum)
#pragma unroll
    for (int qt = 0; qt < 2; ++qt) {
#pragma unroll
      for (int s = 0; s < 2; ++s)
        lacc[qt] = __builtin_amdgcn_mfma_f32_16x16x32_f16(ones, pf[qt][s], lacc[qt], 0, 0, 0);
    }
#pragma unroll
    for (int s = 0; s < 2; ++s) {
#pragma unroll
      for (int dh = 0; dh < 2; ++dh) {
        f16x4 lo = *(const f16x4*)(&Vt[buf][dh * 16 + lm][s * 32 + lg * 4]);
        f16x4 hi = *(const f16x4*)(&Vt[buf][dh * 16 + lm][s * 32 + 16 + lg * 4]);
        f16x8 vf = cat(lo, hi);
#pragma unroll
        for (int qt = 0; qt < 2; ++qt)
          acc[qt][dh] = __builtin_amdgcn_mfma_f32_16x16x32_f16(vf, pf[qt][s], acc[qt][dh], 0, 0, 0);
      }
    }
    if (c < 31) {  // stage next chunk into the other buffer
      *(f16x8*)(&Kt[buf ^ 1][sk][skp * 8]) = kreg;
      *(f16x8*)(&Vt[buf ^ 1][sd][sdp * 8]) = vreg;
    }
    __syncthreads();
  }

#pragma unroll
  for (int qt = 0; qt < 2; ++qt) {
    float inv = 1.0f / lacc[qt][0];
    int q = q0 + qt * 16;
    f16* op = hatt + (size_t)(b * SS + q) * HH + h * DHH;
    f16x4 o0 = {(f16)(acc[qt][0][0] * inv), (f16)(acc[qt][0][1] * inv),
                (f16)(acc[qt][0][2] * inv), (f16)(acc[qt][0][3] * inv)};
    f16x4 o1 = {(f16)(acc[qt][1][0] * inv), (f16)(acc[qt][1][1] * inv),
                (f16)(acc[qt][1][2] * inv), (f16)(acc[qt][1][3] * inv)};
    *(f16x4*)(op + lg * 4) = o0;
    *(f16x4*)(op + 16 + lg * 4) = o1;
  }
}

// ------- fused: out = resid + X@Wl^T + bl; n2 = LN2(out); out += gelu(fs*(n2@W1^T+b1))
__global__ __launch_bounds__(128) void mlp_kernel(const f16* __restrict__ X,
                                                  const f16* __restrict__ Wlf,
                                                  const float* __restrict__ bl,
                                                  const float* __restrict__ resid,
                                                  const float* __restrict__ ln2a,
                                                  const float* __restrict__ ln2b,
                                                  const f16* __restrict__ W1f,
                                                  const float* __restrict__ b1,
                                                  const float* __restrict__ fscale,
                                                  float* __restrict__ out) {
  const int tid = threadIdx.x;
  const int wave = tid >> 6, lane = tid & 63;
  const int lg = lane >> 4, lm = lane & 15;
  const int row = blockIdx.x * 16 + lm;
  const int nc0 = wave * 64;

  __shared__ __align__(16) f16 n2t[16][136];
  __shared__ float red[2][16][2];

  f32x4 acc[4] = {};
  const f16* xr = X + (size_t)row * HH;
#pragma unroll
  for (int ks = 0; ks < 4; ++ks) {
    f16x8 bf = *(const f16x8*)(xr + ks * 32 + lg * 8);
#pragma unroll
    for (int nt = 0; nt < 4; ++nt) {
      f16x8 af = *(const f16x8*)(Wlf + (size_t)(nc0 + nt * 16 + lm) * HH + ks * 32 + lg * 8);
      acc[nt] = __builtin_amdgcn_mfma_f32_16x16x32_f16(af, bf, acc[nt], 0, 0, 0);
    }
  }
  float sum = 0.f, sq = 0.f;
  f32x4 o[4];
#pragma unroll
  for (int nt = 0; nt < 4; ++nt) {
    int n = nc0 + nt * 16 + lg * 4;
    float4 rv = *(const float4*)(resid + (size_t)row * HH + n);
    float4 bv = *(const float4*)(bl + n);
    f32x4 v = acc[nt];
    v[0] += rv.x + bv.x; v[1] += rv.y + bv.y;
    v[2] += rv.z + bv.z; v[3] += rv.w + bv.w;
    o[nt] = v;
    sum += v[0] + v[1] + v[2] + v[3];
    sq += v[0] * v[0] + v[1] * v[1] + v[2] * v[2] + v[3] * v[3];
  }
  sum += __shfl_xor(sum, 16); sum += __shfl_xor(sum, 32);
  sq += __shfl_xor(sq, 16);  sq += __shfl_xor(sq, 32);
  if (lane < 16) { red[wave][lm][0] = sum; red[wave][lm][1] = sq; }
  __syncthreads();
  float ts = red[0][lm][0] + red[1][lm][0];
  float tq = red[0][lm][1] + red[1][lm][1];
  float mean = ts * (1.0f / HH);
  float var = fmaxf((tq - (float)HH * mean * mean) * (1.0f / (HH - 1)), 0.0f);
  float inv = 1.0f / (sqrtf(var) + 1e-6f);
#pragma unroll
  for (int nt = 0; nt < 4; ++nt) {
    int n = nc0 + nt * 16 + lg * 4;
    float4 av = *(const float4*)(ln2a + n);
    float4 b2 = *(const float4*)(ln2b + n);
    f16x4 w;
    w[0] = (f16)(av.x * (o[nt][0] - mean) * inv + b2.x);
    w[1] = (f16)(av.y * (o[nt][1] - mean) * inv + b2.y);
    w[2] = (f16)(av.z * (o[nt][2] - mean) * inv + b2.z);
    w[3] = (f16)(av.w * (o[nt][3] - mean) * inv + b2.w);
    *(f16x4*)(&n2t[lm][n]) = w;
  }
  __syncthreads();

  f32x4 fa[4] = {};
#pragma unroll
  for (int ks = 0; ks < 4; ++ks) {
    f16x8 bf = *(const f16x8*)(&n2t[lm][ks * 32 + lg * 8]);
#pragma unroll
    for (int nt = 0; nt < 4; ++nt) {
      f16x8 af = *(const f16x8*)(W1f + (size_t)(nc0 + nt * 16 + lm) * HH + ks * 32 + lg * 8);
      fa[nt] = __builtin_amdgcn_mfma_f32_16x16x32_f16(af, bf, fa[nt], 0, 0, 0);
    }
  }
  float fs = fscale[row & (SS - 1)];
#pragma unroll
  for (int nt = 0; nt < 4; ++nt) {
    int n = nc0 + nt * 16 + lg * 4;
    float4 bv = *(const float4*)(b1 + n);
    const float* bp = &bv.x;
#pragma unroll
    for (int e = 0; e < 4; ++e) {
      float hf = fs * (fa[nt][e] + bp[e]);
      float u = 0.7978845608028654f * hf * (1.0f + 0.044715f * hf * hf);
      float ex = __builtin_amdgcn_exp2f(u * 2.8853900817779268f);  // exp(2u)
      float t = 1.0f - 2.0f / (ex + 1.0f);
      o[nt][e] += 0.5f * hf * (1.0f + t);
    }
    *(f32x4*)(out + (size_t)row * HH + n) = o[nt];
  }
}

extern "C" void kernel_launch(void* const* d_in, const int* in_sizes, int n_in,
                              void* d_out, int out_size, void* d_ws, size_t ws_size,
                              hipStream_t stream) {
  const float* hidden = (const float*)d_in[0];
  const int* mask = (const int*)d_in[1];
  const float* scalew = (const float*)d_in[2];
  const float* Wl = (const float*)d_in[3];
  const float* bl = (const float*)d_in[4];
  const float* W1 = (const float*)d_in[5];
  const float* b1 = (const float*)d_in[6];
  const float* fscale = (const float*)d_in[7];
  const float* ln1a = (const float*)d_in[8];
  const float* ln1b = (const float*)d_in[9];
  const float* ln2a = (const float*)d_in[10];
  const float* ln2b = (const float*)d_in[11];
  float* out = (float*)d_out;

  const size_t NE = (size_t)BB * SS * HH;  // 2M elements
  f16* n1 = (f16*)d_ws;
  f16* n1T = n1 + NE;
  f16* hattf = n1T + NE;
  f16* Wlf = hattf + NE;
  f16* W1f = Wlf + HH * HH;
  float* mb = (float*)(W1f + HH * HH);

  const int rows = BB * SS;
  prep_kernel<<<48, 256, 0, stream>>>(Wl, W1, mask, Wlf, W1f, mb);
  ln_kernel<<<rows / 16, 256, 0, stream>>>(hidden, ln1a, ln1b, n1, n1T);
  attn_kernel<<<BB * NHH * (SS / 128), 256, 0, stream>>>(n1, n1T, mb, scalew, hattf);
  mlp_kernel<<<rows / 16, 128, 0, stream>>>(hattf, Wlf, bl, hidden, ln2a, ln2b,
                                            W1f, b1, fscale, out);
}

// Round 7
// 53.112 us; speedup vs baseline: 2.4351x; 1.2194x over previous
//
#include <hip/hip_runtime.h>

#define BB 8
#define SS 2048
#define HH 128
#define NHH 4
#define DHH 32

typedef _Float16 f16;
typedef f16 f16x4 __attribute__((ext_vector_type(4)));
typedef f16 f16x8 __attribute__((ext_vector_type(8)));
typedef float f32x4 __attribute__((ext_vector_type(4)));

__device__ __forceinline__ f16x8 cat(f16x4 a, f16x4 b) {
  return (f16x8){a[0], a[1], a[2], a[3], b[0], b[1], b[2], b[3]};
}

// hardware transpose read (R2/R3/R5-proven). CALLER MUST wait lgkmcnt(0) +
// sched_barrier(0) before using the result (rule #18).
__device__ __forceinline__ f16x4 tr_read(const f16* p) {
  f16x4 d;
  asm volatile("ds_read_b64_tr_b16 %0, %1"
               : "=v"(d)
               : "v"((__attribute__((address_space(3))) const f16*)p)
               : "memory");
  return d;
}

// ---------------- LayerNorm -> n1 (row-major f16) ----------------
__global__ __launch_bounds__(256) void ln_kernel(const float* __restrict__ x,
                                                 const float* __restrict__ ga,
                                                 const float* __restrict__ gb,
                                                 f16* __restrict__ n1) {
  const int tid = threadIdx.x;
  const int wave = tid >> 6, lane = tid & 63;
  const int grp = lane >> 4, lm = lane & 15;
  const int r = wave * 4 + grp;  // local row 0..15
  const size_t row = (size_t)blockIdx.x * 16 + r;

  const float* xr = x + row * HH + lm * 8;
  float4 v0 = *(const float4*)(xr);
  float4 v1 = *(const float4*)(xr + 4);
  float xv[8] = {v0.x, v0.y, v0.z, v0.w, v1.x, v1.y, v1.z, v1.w};
  float sum = 0.f, sq = 0.f;
#pragma unroll
  for (int j = 0; j < 8; ++j) { sum += xv[j]; sq += xv[j] * xv[j]; }
#pragma unroll
  for (int m = 1; m < 16; m <<= 1) {
    sum += __shfl_xor(sum, m);
    sq += __shfl_xor(sq, m);
  }
  float mean = sum * (1.0f / HH);
  float var = fmaxf((sq - (float)HH * mean * mean) * (1.0f / (HH - 1)), 0.0f);
  float inv = 1.0f / (sqrtf(var) + 1e-6f);

  float4 a0 = *(const float4*)(ga + lm * 8);
  float4 a1 = *(const float4*)(ga + lm * 8 + 4);
  float4 b0 = *(const float4*)(gb + lm * 8);
  float4 b1 = *(const float4*)(gb + lm * 8 + 4);
  float av[8] = {a0.x, a0.y, a0.z, a0.w, a1.x, a1.y, a1.z, a1.w};
  float bv[8] = {b0.x, b0.y, b0.z, b0.w, b1.x, b1.y, b1.z, b1.w};
  f16x8 w;
#pragma unroll
  for (int j = 0; j < 8; ++j) w[j] = (f16)(av[j] * (xv[j] - mean) * inv + bv[j]);
  *(f16x8*)(n1 + row * HH + lm * 8) = w;
}

// ------- prep: weights->f16 (blocks 0..31) + per-batch mask scan (blocks 32..39)
__global__ __launch_bounds__(256) void prep_kernel(const float* __restrict__ Wl,
                                                   const float* __restrict__ W1,
                                                   const int* __restrict__ mask,
                                                   f16* __restrict__ Wlf,
                                                   f16* __restrict__ W1f,
                                                   int* __restrict__ idx,
                                                   int* __restrict__ nkcnt,
                                                   int* __restrict__ nkpad) {
  const int t = threadIdx.x;
  if (blockIdx.x < 32) {
    int g = blockIdx.x * 256 + t;
    if (g < 4096) {
      float4 w = ((const float4*)Wl)[g];
      f16x4 o = {(f16)w.x, (f16)w.y, (f16)w.z, (f16)w.w};
      ((f16x4*)Wlf)[g] = o;
    } else {
      float4 w = ((const float4*)W1)[g - 4096];
      f16x4 o = {(f16)w.x, (f16)w.y, (f16)w.z, (f16)w.w};
      ((f16x4*)W1f)[g - 4096] = o;
    }
    return;
  }
  // mask scan for batch b
  const int b = blockIdx.x - 32;
  __shared__ int ps[256];
  int m8[8];
  int cnt = 0;
  const int* mp = mask + b * SS + t * 8;
#pragma unroll
  for (int j = 0; j < 8; ++j) {
    m8[j] = mp[j];
    cnt += (m8[j] != 0);
  }
  ps[t] = cnt;
  __syncthreads();
  for (int off = 1; off < 256; off <<= 1) {
    int v = (t >= off) ? ps[t - off] : 0;
    __syncthreads();
    ps[t] += v;
    __syncthreads();
  }
  int pos = ps[t] - cnt;  // exclusive prefix
#pragma unroll
  for (int j = 0; j < 8; ++j) {
    if (m8[j] != 0) idx[b * SS + pos++] = t * 8 + j;
  }
  if (t == 255) {
    int nk = ps[255];
    nkcnt[b] = nk;
    int np = (nk + 63) & ~63;
    if (np == 0) np = 64;
    nkpad[b] = np;
  }
}

// ------- gather: kcomp[b][j][128] = n1[b][idx[j]][:], vcompT[b][d][j], biasc --
// grid = BB*128 blocks, 256 thr; block handles 16 j-rows (ln_kernel pattern)
__global__ __launch_bounds__(256) void gather_kernel(const f16* __restrict__ n1,
                                                     const int* __restrict__ idx,
                                                     const int* __restrict__ nkcnt,
                                                     const int* __restrict__ nkpad,
                                                     f16* __restrict__ kcomp,
                                                     f16* __restrict__ vcompT,
                                                     float* __restrict__ biasc) {
  const int b = blockIdx.x >> 7;
  const int j0 = (blockIdx.x & 127) * 16;
  if (j0 >= nkpad[b]) return;
  const int nk = nkcnt[b];

  const int tid = threadIdx.x;
  const int wave = tid >> 6, lane = tid & 63;
  const int grp = lane >> 4, lm = lane & 15;
  const int r = wave * 4 + grp;  // local j 0..15
  const int j = j0 + r;

  __shared__ __align__(16) f16 Tl[8 * 520];  // 8 panels [16j][16d], pad 8

  f16x8 v = {};
  if (j < nk) {
    int s = idx[b * SS + j];
    v = *(const f16x8*)(n1 + ((size_t)b * SS + s) * HH + lm * 8);
  }
  *(f16x8*)(kcomp + ((size_t)b * SS + j) * HH + lm * 8) = v;
  if (lm == 0) biasc[b * SS + j] = (j < nk) ? -5.7707801636f : -1.5e9f;
  *(f16x8*)(&Tl[(lm >> 1) * 520 + r * 16 + (lm & 1) * 8]) = v;
  __syncthreads();

  const int p0 = wave * 2;
  f16x4 tv0 = tr_read(&Tl[p0 * 520] + lane * 4);  // elem jj = panel[j=4*(lane>>4)+jj][d=lm]
  f16x4 tv1 = tr_read(&Tl[(p0 + 1) * 520] + lane * 4);
  asm volatile("s_waitcnt lgkmcnt(0)" ::: "memory");
  __builtin_amdgcn_sched_barrier(0);
  int d0 = p0 * 16 + lm;
  *(f16x4*)(vcompT + ((size_t)b * HH + d0) * SS + j0 + (lane >> 4) * 4) = tv0;
  int d1 = (p0 + 1) * 16 + lm;
  *(f16x4*)(vcompT + ((size_t)b * HH + d1) * SS + j0 + (lane >> 4) * 4) = tv1;
}

// ------- attention over compacted keys: shared dbuf LDS tiles, 32 q/wave -----
// grid = B*NH*(S/128) = 512; block 256 = 4 waves; chunk = 64 compacted keys
__global__ __launch_bounds__(256, 2) void attn_kernel(const f16* __restrict__ n1,
                                                      const f16* __restrict__ kcomp,
                                                      const f16* __restrict__ vcompT,
                                                      const float* __restrict__ biasc,
                                                      const int* __restrict__ nkpad,
                                                      const float* __restrict__ scalew,
                                                      f16* __restrict__ hatt) {
  const int tid = threadIdx.x;
  const int qb = blockIdx.x & 15;
  const int h = (blockIdx.x >> 4) & 3;
  const int b = blockIdx.x >> 6;
  const int wave = tid >> 6, lane = tid & 63;
  const int lg = lane >> 4, lm = lane & 15;
  const int ns = nkpad[b] >> 6;  // chunks of 64

  __shared__ __align__(16) f16 Kt[2][64][40];  // key-major, 80B stride
  __shared__ __align__(16) f16 Vt[2][32][72];  // d-major, 144B stride

  const f16* __restrict__ nb = n1 + (size_t)b * SS * HH + h * DHH;
  const f16* __restrict__ kb = kcomp + (size_t)b * SS * HH + h * DHH;
  const f16* __restrict__ vb = vcompT + ((size_t)b * HH + h * DHH) * SS;
  const float* __restrict__ mbb = biasc + b * SS;

  const int q0 = qb * 128 + wave * 32 + lm;
  f16x8 qf[2];
  float sc2[2];
#pragma unroll
  for (int qt = 0; qt < 2; ++qt) {
    int q = q0 + qt * 16;
    qf[qt] = *(const f16x8*)(nb + (size_t)q * HH + lg * 8);
    sc2[qt] = scalew[h * SS + q] * 0.2550680718664f;  // (1/sqrt32)*log2e
  }

  // staging: K: thread -> key tid>>2, 16B part tid&3 ; V: d tid>>3, part tid&7
  const int sk = tid >> 2, skp = tid & 3;
  const int sd = tid >> 3, sdp = tid & 7;
  const f16* gK = kb + (size_t)sk * HH + skp * 8;
  const f16* gV = vb + (size_t)sd * SS + sdp * 8;

  const f32x4 zero = {0.f, 0.f, 0.f, 0.f};
  f32x4 acc[2][2] = {{zero, zero}, {zero, zero}};  // [qt][dh]
  f32x4 lacc[2] = {zero, zero};
  const f16x8 ones = {(f16)1, (f16)1, (f16)1, (f16)1, (f16)1, (f16)1, (f16)1, (f16)1};

  f16x8 kreg = *(const f16x8*)(gK);
  f16x8 vreg = *(const f16x8*)(gV);
  *(f16x8*)(&Kt[0][sk][skp * 8]) = kreg;
  *(f16x8*)(&Vt[0][sd][sdp * 8]) = vreg;
  __syncthreads();

  for (int c = 0; c < ns; ++c) {
    const int buf = c & 1;
    const int k0 = c * 64;
    if (c + 1 < ns) {  // issue next chunk's global loads early
      kreg = *(const f16x8*)(gK + (size_t)(k0 + 64) * HH);
      vreg = *(const f16x8*)(gV + k0 + 64);
    }
    float4 mv[4];
#pragma unroll
    for (int t = 0; t < 4; ++t) mv[t] = *(const float4*)(mbb + k0 + t * 16 + lg * 4);

    f16x8 kf[4];
#pragma unroll
    for (int t = 0; t < 4; ++t) kf[t] = *(const f16x8*)(&Kt[buf][t * 16 + lm][lg * 8]);

    f16x8 pf[2][2];
#pragma unroll
    for (int qt = 0; qt < 2; ++qt) {
#pragma unroll
      for (int t = 0; t < 4; ++t) {
        f32x4 st = __builtin_amdgcn_mfma_f32_16x16x32_f16(kf[t], qf[qt], zero, 0, 0, 0);
        const float* mp = &mv[t].x;
#pragma unroll
        for (int r = 0; r < 4; ++r) {
          float pe = __builtin_amdgcn_exp2f(st[r] * sc2[qt] + mp[r]);
          pf[qt][t >> 1][(t & 1) * 4 + r] = (f16)pe;
        }
      }
    }
    // denominator on the matrix pipe: lacc += 1^T * P
#pragma unroll
    for (int qt = 0; qt < 2; ++qt) {
#pragma unroll
      for (int s = 0; s < 2; ++s)
        lacc[qt] = __builtin_amdgcn_mfma_f32_16x16x32_f16(ones, pf[qt][s], lacc[qt], 0, 0, 0);
    }
#pragma unroll
    for (int s = 0; s < 2; ++s) {
#pragma unroll
      for (int dh = 0; dh < 2; ++dh) {
        f16x4 lo = *(const f16x4*)(&Vt[buf][dh * 16 + lm][s * 32 + lg * 4]);
        f16x4 hi = *(const f16x4*)(&Vt[buf][dh * 16 + lm][s * 32 + 16 + lg * 4]);
        f16x8 vf = cat(lo, hi);
#pragma unroll
        for (int qt = 0; qt < 2; ++qt)
          acc[qt][dh] = __builtin_amdgcn_mfma_f32_16x16x32_f16(vf, pf[qt][s], acc[qt][dh], 0, 0, 0);
      }
    }
    if (c + 1 < ns) {  // stage next chunk into the other buffer
      *(f16x8*)(&Kt[buf ^ 1][sk][skp * 8]) = kreg;
      *(f16x8*)(&Vt[buf ^ 1][sd][sdp * 8]) = vreg;
    }
    __syncthreads();
  }

#pragma unroll
  for (int qt = 0; qt < 2; ++qt) {
    float inv = 1.0f / lacc[qt][0];
    int q = q0 + qt * 16;
    f16* op = hatt + (size_t)(b * SS + q) * HH + h * DHH;
    f16x4 o0 = {(f16)(acc[qt][0][0] * inv), (f16)(acc[qt][0][1] * inv),
                (f16)(acc[qt][0][2] * inv), (f16)(acc[qt][0][3] * inv)};
    f16x4 o1 = {(f16)(acc[qt][1][0] * inv), (f16)(acc[qt][1][1] * inv),
                (f16)(acc[qt][1][2] * inv), (f16)(acc[qt][1][3] * inv)};
    *(f16x4*)(op + lg * 4) = o0;
    *(f16x4*)(op + 16 + lg * 4) = o1;
  }
}

// ------- fused MLP: 32 rows/block, 256 thr (4 waves x 32 cols) ---------------
// out = resid + X@Wl^T + bl; n2 = LN2(out); out += gelu(fs*(n2@W1^T+b1))
__global__ __launch_bounds__(256) void mlp_kernel(const f16* __restrict__ X,
                                                  const f16* __restrict__ Wlf,
                                                  const float* __restrict__ bl,
                                                  const float* __restrict__ resid,
                                                  const float* __restrict__ ln2a,
                                                  const float* __restrict__ ln2b,
                                                  const f16* __restrict__ W1f,
                                                  const float* __restrict__ b1,
                                                  const float* __restrict__ fscale,
                                                  float* __restrict__ out) {
  const int tid = threadIdx.x;
  const int wave = tid >> 6, lane = tid & 63;
  const int lg = lane >> 4, lm = lane & 15;
  const int rbase = blockIdx.x * 32;
  const int nc0 = wave * 32;

  __shared__ __align__(16) f16 n2t[32][136];
  __shared__ float red[4][32][2];

  f32x4 acc[2][2] = {};
  const f16* xr0 = X + (size_t)(rbase + lm) * HH;
  const f16* xr1 = X + (size_t)(rbase + 16 + lm) * HH;
#pragma unroll
  for (int ks = 0; ks < 4; ++ks) {
    f16x8 bf0 = *(const f16x8*)(xr0 + ks * 32 + lg * 8);
    f16x8 bf1 = *(const f16x8*)(xr1 + ks * 32 + lg * 8);
#pragma unroll
    for (int nt = 0; nt < 2; ++nt) {
      f16x8 af = *(const f16x8*)(Wlf + (size_t)(nc0 + nt * 16 + lm) * HH + ks * 32 + lg * 8);
      acc[0][nt] = __builtin_amdgcn_mfma_f32_16x16x32_f16(af, bf0, acc[0][nt], 0, 0, 0);
      acc[1][nt] = __builtin_amdgcn_mfma_f32_16x16x32_f16(af, bf1, acc[1][nt], 0, 0, 0);
    }
  }
  float sum[2] = {0.f, 0.f}, sq[2] = {0.f, 0.f};
  f32x4 o[2][2];
#pragma unroll
  for (int g = 0; g < 2; ++g) {
    int row = rbase + g * 16 + lm;
#pragma unroll
    for (int nt = 0; nt < 2; ++nt) {
      int n = nc0 + nt * 16 + lg * 4;
      float4 rv = *(const float4*)(resid + (size_t)row * HH + n);
      float4 bv = *(const float4*)(bl + n);
      f32x4 v = acc[g][nt];
      v[0] += rv.x + bv.x; v[1] += rv.y + bv.y;
      v[2] += rv.z + bv.z; v[3] += rv.w + bv.w;
      o[g][nt] = v;
      sum[g] += v[0] + v[1] + v[2] + v[3];
      sq[g] += v[0] * v[0] + v[1] * v[1] + v[2] * v[2] + v[3] * v[3];
    }
    sum[g] += __shfl_xor(sum[g], 16); sum[g] += __shfl_xor(sum[g], 32);
    sq[g] += __shfl_xor(sq[g], 16);  sq[g] += __shfl_xor(sq[g], 32);
  }
  if (lane < 16) {
#pragma unroll
    for (int g = 0; g < 2; ++g) {
      red[wave][g * 16 + lm][0] = sum[g];
      red[wave][g * 16 + lm][1] = sq[g];
    }
  }
  __syncthreads();
#pragma unroll
  for (int g = 0; g < 2; ++g) {
    int lr = g * 16 + lm;
    float ts = red[0][lr][0] + red[1][lr][0] + red[2][lr][0] + red[3][lr][0];
    float tq = red[0][lr][1] + red[1][lr][1] + red[2][lr][1] + red[3][lr][1];
    float mean = ts * (1.0f / HH);
    float var = fmaxf((tq - (float)HH * mean * mean) * (1.0f / (HH - 1)), 0.0f);
    float inv = 1.0f / (sqrtf(var) + 1e-6f);
#pragma unroll
    for (int nt = 0; nt < 2; ++nt) {
      int n = nc0 + nt * 16 + lg * 4;
      float4 av = *(const float4*)(ln2a + n);
      float4 b2 = *(const float4*)(ln2b + n);
      f16x4 w;
      w[0] = (f16)(av.x * (o[g][nt][0] - mean) * inv + b2.x);
      w[1] = (f16)(av.y * (o[g][nt][1] - mean) * inv + b2.y);
      w[2] = (f16)(av.z * (o[g][nt][2] - mean) * inv + b2.z);
      w[3] = (f16)(av.w * (o[g][nt][3] - mean) * inv + b2.w);
      *(f16x4*)(&n2t[lr][n]) = w;
    }
  }
  __syncthreads();

  f32x4 fa[2][2] = {};
#pragma unroll
  for (int ks = 0; ks < 4; ++ks) {
    f16x8 bf0 = *(const f16x8*)(&n2t[lm][ks * 32 + lg * 8]);
    f16x8 bf1 = *(const f16x8*)(&n2t[16 + lm][ks * 32 + lg * 8]);
#pragma unroll
    for (int nt = 0; nt < 2; ++nt) {
      f16x8 af = *(const f16x8*)(W1f + (size_t)(nc0 + nt * 16 + lm) * HH + ks * 32 + lg * 8);
      fa[0][nt] = __builtin_amdgcn_mfma_f32_16x16x32_f16(af, bf0, fa[0][nt], 0, 0, 0);
      fa[1][nt] = __builtin_amdgcn_mfma_f32_16x16x32_f16(af, bf1, fa[1][nt], 0, 0, 0);
    }
  }
#pragma unroll
  for (int g = 0; g < 2; ++g) {
    int row = rbase + g * 16 + lm;
    float fs = fscale[row & (SS - 1)];
#pragma unroll
    for (int nt = 0; nt < 2; ++nt) {
      int n = nc0 + nt * 16 + lg * 4;
      float4 bv = *(const float4*)(b1 + n);
      const float* bp = &bv.x;
#pragma unroll
      for (int e = 0; e < 4; ++e) {
        float hf = fs * (fa[g][nt][e] + bp[e]);
        float u = 0.7978845608028654f * hf * (1.0f + 0.044715f * hf * hf);
        float ex = __builtin_amdgcn_exp2f(u * 2.8853900817779268f);  // exp(2u)
        float t = 1.0f - 2.0f / (ex + 1.0f);
        o[g][nt][e] += 0.5f * hf * (1.0f + t);
      }
      *(f32x4*)(out + (size_t)row * HH + n) = o[g][nt];
    }
  }
}

extern "C" void kernel_launch(void* const* d_in, const int* in_sizes, int n_in,
                              void* d_out, int out_size, void* d_ws, size_t ws_size,
                              hipStream_t stream) {
  const float* hidden = (const float*)d_in[0];
  const int* mask = (const int*)d_in[1];
  const float* scalew = (const float*)d_in[2];
  const float* Wl = (const float*)d_in[3];
  const float* bl = (const float*)d_in[4];
  const float* W1 = (const float*)d_in[5];
  const float* b1 = (const float*)d_in[6];
  const float* fscale = (const float*)d_in[7];
  const float* ln1a = (const float*)d_in[8];
  const float* ln1b = (const float*)d_in[9];
  const float* ln2a = (const float*)d_in[10];
  const float* ln2b = (const float*)d_in[11];
  float* out = (float*)d_out;

  const size_t NE = (size_t)BB * SS * HH;  // 2M elements
  f16* n1 = (f16*)d_ws;
  f16* hattf = n1 + NE;
  f16* kcomp = hattf + NE;
  f16* vcompT = kcomp + NE;
  f16* Wlf = vcompT + NE;
  f16* W1f = Wlf + HH * HH;
  float* biasc = (float*)(W1f + HH * HH);
  int* idx = (int*)(biasc + BB * SS);
  int* nkcnt = idx + BB * SS;
  int* nkpad = nkcnt + BB;

  const int rows = BB * SS;
  prep_kernel<<<40, 256, 0, stream>>>(Wl, W1, mask, Wlf, W1f, idx, nkcnt, nkpad);
  ln_kernel<<<rows / 16, 256, 0, stream>>>(hidden, ln1a, ln1b, n1);
  gather_kernel<<<BB * 128, 256, 0, stream>>>(n1, idx, nkcnt, nkpad, kcomp, vcompT, biasc);
  attn_kernel<<<BB * NHH * (SS / 128), 256, 0, stream>>>(n1, kcomp, vcompT, biasc,
                                                         nkpad, scalew, hattf);
  mlp_kernel<<<rows / 32, 256, 0, stream>>>(hattf, Wlf, bl, hidden, ln2a, ln2b,
                                            W1f, b1, fscale, out);
}

// Round 8
// 45.918 us; speedup vs baseline: 2.8167x; 1.1567x over previous
//
#include <hip/hip_runtime.h>

#define BB 8
#define SS 2048
#define HH 128
#define NHH 4
#define DHH 32

typedef _Float16 f16;
typedef f16 f16x4 __attribute__((ext_vector_type(4)));
typedef f16 f16x8 __attribute__((ext_vector_type(8)));
typedef float f32x4 __attribute__((ext_vector_type(4)));

#define BIAS0 -5.7707801636f  /* (-4)*log2e */

__device__ __forceinline__ f16x8 cat(f16x4 a, f16x4 b) {
  return (f16x8){a[0], a[1], a[2], a[3], b[0], b[1], b[2], b[3]};
}

// hardware transpose read (R2/R3/R5-proven): on a contiguous [16 rows][16 cols]
// f16 panel, tr_read(panel + lane*4) gives lane(lg,lm) elem j = panel[4*lg+j][lm].
// CALLER MUST wait lgkmcnt(0) + sched_barrier(0) before use (rule #18).
__device__ __forceinline__ f16x4 tr_read(const f16* p) {
  f16x4 d;
  asm volatile("ds_read_b64_tr_b16 %0, %1"
               : "=v"(d)
               : "v"((__attribute__((address_space(3))) const f16*)p)
               : "memory");
  return d;
}

// ---- stage1: LN1 (blocks 0..1023) + weights->f16 (1024..1055) + mask scan (1056..1063)
__global__ __launch_bounds__(256) void stage1_kernel(const float* __restrict__ x,
                                                     const float* __restrict__ ga,
                                                     const float* __restrict__ gb,
                                                     const float* __restrict__ Wl,
                                                     const float* __restrict__ W1,
                                                     const int* __restrict__ mask,
                                                     f16* __restrict__ n1,
                                                     f16* __restrict__ Wlf,
                                                     f16* __restrict__ W1f,
                                                     int* __restrict__ idx,
                                                     int* __restrict__ nkcnt,
                                                     int* __restrict__ nkpad) {
  const int tid = threadIdx.x;
  if (blockIdx.x < 1024) {  // ---- LayerNorm path: 16 rows/block
    const int wave = tid >> 6, lane = tid & 63;
    const int grp = lane >> 4, lm = lane & 15;
    const int r = wave * 4 + grp;
    const size_t row = (size_t)blockIdx.x * 16 + r;

    const float* xr = x + row * HH + lm * 8;
    float4 v0 = *(const float4*)(xr);
    float4 v1 = *(const float4*)(xr + 4);
    float xv[8] = {v0.x, v0.y, v0.z, v0.w, v1.x, v1.y, v1.z, v1.w};
    float sum = 0.f, sq = 0.f;
#pragma unroll
    for (int j = 0; j < 8; ++j) { sum += xv[j]; sq += xv[j] * xv[j]; }
#pragma unroll
    for (int m = 1; m < 16; m <<= 1) {
      sum += __shfl_xor(sum, m);
      sq += __shfl_xor(sq, m);
    }
    float mean = sum * (1.0f / HH);
    float var = fmaxf((sq - (float)HH * mean * mean) * (1.0f / (HH - 1)), 0.0f);
    float inv = 1.0f / (sqrtf(var) + 1e-6f);

    float4 a0 = *(const float4*)(ga + lm * 8);
    float4 a1 = *(const float4*)(ga + lm * 8 + 4);
    float4 b0 = *(const float4*)(gb + lm * 8);
    float4 b1 = *(const float4*)(gb + lm * 8 + 4);
    float av[8] = {a0.x, a0.y, a0.z, a0.w, a1.x, a1.y, a1.z, a1.w};
    float bv[8] = {b0.x, b0.y, b0.z, b0.w, b1.x, b1.y, b1.z, b1.w};
    f16x8 w;
#pragma unroll
    for (int j = 0; j < 8; ++j) w[j] = (f16)(av[j] * (xv[j] - mean) * inv + bv[j]);
    *(f16x8*)(n1 + row * HH + lm * 8) = w;
    return;
  }
  if (blockIdx.x < 1056) {  // ---- weight conversion path
    int g = (blockIdx.x - 1024) * 256 + tid;
    if (g < 4096) {
      float4 w = ((const float4*)Wl)[g];
      f16x4 o = {(f16)w.x, (f16)w.y, (f16)w.z, (f16)w.w};
      ((f16x4*)Wlf)[g] = o;
    } else {
      float4 w = ((const float4*)W1)[g - 4096];
      f16x4 o = {(f16)w.x, (f16)w.y, (f16)w.z, (f16)w.w};
      ((f16x4*)W1f)[g - 4096] = o;
    }
    return;
  }
  // ---- mask scan path: one block per batch
  const int b = blockIdx.x - 1056;
  __shared__ int ps[256];
  int m8[8];
  int cnt = 0;
  const int* mp = mask + b * SS + tid * 8;
#pragma unroll
  for (int j = 0; j < 8; ++j) {
    m8[j] = mp[j];
    cnt += (m8[j] != 0);
  }
  ps[tid] = cnt;
  __syncthreads();
  for (int off = 1; off < 256; off <<= 1) {
    int v = (tid >= off) ? ps[tid - off] : 0;
    __syncthreads();
    ps[tid] += v;
    __syncthreads();
  }
  int pos = ps[tid] - cnt;  // exclusive prefix
#pragma unroll
  for (int j = 0; j < 8; ++j) {
    if (m8[j] != 0) idx[b * SS + pos++] = tid * 8 + j;
  }
  __syncthreads();
  int nkv = ps[255];
  int npv = (nkv + 63) & ~63;
  if (npv == 0) npv = 64;
  for (int jj = nkv + tid; jj < npv; jj += 256) idx[b * SS + jj] = 0;  // safe pad rows
  if (tid == 255) { nkcnt[b] = nkv; nkpad[b] = npv; }
}

// ---- attention: self-gathering, K-tile doubles as V via tr_read --------------
// grid = B*NH*(S/128) = 512; block 256 = 4 waves; wave = 32 queries; chunk = 64 keys
__global__ __launch_bounds__(256, 2) void attn_kernel(const f16* __restrict__ n1,
                                                      const int* __restrict__ idx,
                                                      const int* __restrict__ nkcnt,
                                                      const int* __restrict__ nkpad,
                                                      const float* __restrict__ scalew,
                                                      f16* __restrict__ hatt) {
  const int tid = threadIdx.x;
  const int qb = blockIdx.x & 15;
  const int h = (blockIdx.x >> 4) & 3;
  const int b = blockIdx.x >> 6;
  const int wave = tid >> 6, lane = tid & 63;
  const int lg = lane >> 4, lm = lane & 15;
  const int nk = nkcnt[b];
  const int ns = nkpad[b] >> 6;

  __shared__ __align__(16) f16 Kt[2][2][64][16];  // [buf][dgroup][key][16d]
  __shared__ __align__(16) int idxL[SS];          // 8 KB compacted-index cache

  const f16* __restrict__ nb = n1 + (size_t)b * SS * HH + h * DHH;

  const int np = ns << 6;
  for (int j = tid * 4; j < np; j += 1024)
    *(int4*)&idxL[j] = *(const int4*)(idx + b * SS + j);

  const int q0 = qb * 128 + wave * 32 + lm;
  f16x8 qf[2];
  float sc2[2];
#pragma unroll
  for (int qt = 0; qt < 2; ++qt) {
    int q = q0 + qt * 16;
    qf[qt] = *(const f16x8*)(nb + (size_t)q * HH + lg * 8);
    sc2[qt] = scalew[h * SS + q] * 0.2550680718664f;  // (1/sqrt32)*log2e
  }

  const int sk = tid >> 2, sp = tid & 3;  // staging: key sk, 16B part sp

  const f32x4 zero = {0.f, 0.f, 0.f, 0.f};
  f32x4 acc[2][2] = {{zero, zero}, {zero, zero}};  // [qt][dh]
  f32x4 lacc[2] = {zero, zero};
  const f16x8 ones = {(f16)1, (f16)1, (f16)1, (f16)1, (f16)1, (f16)1, (f16)1, (f16)1};

  __syncthreads();  // idxL ready
  {
    int row = idxL[sk];
    f16x8 kreg = *(const f16x8*)(nb + (size_t)row * HH + sp * 8);
    *(f16x8*)(&Kt[0][sp >> 1][sk][(sp & 1) * 8]) = kreg;
  }
  __syncthreads();

  for (int c = 0; c < ns; ++c) {
    const int buf = c & 1;
    const int k0 = c * 64;
    f16x8 kreg;
    if (c + 1 < ns) {  // issue next chunk's gather early
      int row = idxL[k0 + 64 + sk];
      kreg = *(const f16x8*)(nb + (size_t)row * HH + sp * 8);
    }
    // V^T fragments first (so compiler's kf waits cover them) — 8 tr reads
    f16x4 t0a = tr_read(&Kt[buf][0][0][0] + lane * 4);   // dh0 keys 0-15
    f16x4 t0b = tr_read(&Kt[buf][0][16][0] + lane * 4);  // dh0 keys 16-31
    f16x4 t0c = tr_read(&Kt[buf][0][32][0] + lane * 4);
    f16x4 t0d = tr_read(&Kt[buf][0][48][0] + lane * 4);
    f16x4 t1a = tr_read(&Kt[buf][1][0][0] + lane * 4);   // dh1
    f16x4 t1b = tr_read(&Kt[buf][1][16][0] + lane * 4);
    f16x4 t1c = tr_read(&Kt[buf][1][32][0] + lane * 4);
    f16x4 t1d = tr_read(&Kt[buf][1][48][0] + lane * 4);

    f16x8 kf[4];
#pragma unroll
    for (int t = 0; t < 4; ++t)
      kf[t] = *(const f16x8*)(&Kt[buf][lg >> 1][t * 16 + lm][(lg & 1) * 8]);

    const bool tail = (k0 + 64 > nk);
    f16x8 pf[2][2];
#pragma unroll
    for (int qt = 0; qt < 2; ++qt) {
#pragma unroll
      for (int t = 0; t < 4; ++t) {
        f32x4 st = __builtin_amdgcn_mfma_f32_16x16x32_f16(kf[t], qf[qt], zero, 0, 0, 0);
#pragma unroll
        for (int r = 0; r < 4; ++r) {
          float pe = __builtin_amdgcn_exp2f(st[r] * sc2[qt] + BIAS0);
          if (tail) pe = (k0 + t * 16 + lg * 4 + r < nk) ? pe : 0.0f;
          pf[qt][t >> 1][(t & 1) * 4 + r] = (f16)pe;
        }
      }
    }
    // denominator on matrix pipe
#pragma unroll
    for (int qt = 0; qt < 2; ++qt) {
#pragma unroll
      for (int s = 0; s < 2; ++s)
        lacc[qt] = __builtin_amdgcn_mfma_f32_16x16x32_f16(ones, pf[qt][s], lacc[qt], 0, 0, 0);
    }

    asm volatile("s_waitcnt lgkmcnt(0)" ::: "memory");
    __builtin_amdgcn_sched_barrier(0);

    f16x8 vf;
    vf = cat(t0a, t0b);  // dh0, keys 0-31
#pragma unroll
    for (int qt = 0; qt < 2; ++qt)
      acc[qt][0] = __builtin_amdgcn_mfma_f32_16x16x32_f16(vf, pf[qt][0], acc[qt][0], 0, 0, 0);
    vf = cat(t1a, t1b);  // dh1, keys 0-31
#pragma unroll
    for (int qt = 0; qt < 2; ++qt)
      acc[qt][1] = __builtin_amdgcn_mfma_f32_16x16x32_f16(vf, pf[qt][0], acc[qt][1], 0, 0, 0);
    vf = cat(t0c, t0d);  // dh0, keys 32-63
#pragma unroll
    for (int qt = 0; qt < 2; ++qt)
      acc[qt][0] = __builtin_amdgcn_mfma_f32_16x16x32_f16(vf, pf[qt][1], acc[qt][0], 0, 0, 0);
    vf = cat(t1c, t1d);  // dh1, keys 32-63
#pragma unroll
    for (int qt = 0; qt < 2; ++qt)
      acc[qt][1] = __builtin_amdgcn_mfma_f32_16x16x32_f16(vf, pf[qt][1], acc[qt][1], 0, 0, 0);

    if (c + 1 < ns)
      *(f16x8*)(&Kt[buf ^ 1][sp >> 1][sk][(sp & 1) * 8]) = kreg;
    __syncthreads();
  }

#pragma unroll
  for (int qt = 0; qt < 2; ++qt) {
    float inv = 1.0f / lacc[qt][0];
    int q = q0 + qt * 16;
    f16* op = hatt + (size_t)(b * SS + q) * HH + h * DHH;
    f16x4 o0 = {(f16)(acc[qt][0][0] * inv), (f16)(acc[qt][0][1] * inv),
                (f16)(acc[qt][0][2] * inv), (f16)(acc[qt][0][3] * inv)};
    f16x4 o1 = {(f16)(acc[qt][1][0] * inv), (f16)(acc[qt][1][1] * inv),
                (f16)(acc[qt][1][2] * inv), (f16)(acc[qt][1][3] * inv)};
    *(f16x4*)(op + lg * 4) = o0;
    *(f16x4*)(op + 16 + lg * 4) = o1;
  }
}

// ------- fused MLP: 32 rows/block, 256 thr (4 waves x 32 cols) ---------------
__global__ __launch_bounds__(256) void mlp_kernel(const f16* __restrict__ X,
                                                  const f16* __restrict__ Wlf,
                                                  const float* __restrict__ bl,
                                                  const float* __restrict__ resid,
                                                  const float* __restrict__ ln2a,
                                                  const float* __restrict__ ln2b,
                                                  const f16* __restrict__ W1f,
                                                  const float* __restrict__ b1,
                                                  const float* __restrict__ fscale,
                                                  float* __restrict__ out) {
  const int tid = threadIdx.x;
  const int wave = tid >> 6, lane = tid & 63;
  const int lg = lane >> 4, lm = lane & 15;
  const int rbase = blockIdx.x * 32;
  const int nc0 = wave * 32;

  __shared__ __align__(16) f16 n2t[32][136];
  __shared__ float red[4][32][2];

  f32x4 acc[2][2] = {};
  const f16* xr0 = X + (size_t)(rbase + lm) * HH;
  const f16* xr1 = X + (size_t)(rbase + 16 + lm) * HH;
#pragma unroll
  for (int ks = 0; ks < 4; ++ks) {
    f16x8 bf0 = *(const f16x8*)(xr0 + ks * 32 + lg * 8);
    f16x8 bf1 = *(const f16x8*)(xr1 + ks * 32 + lg * 8);
#pragma unroll
    for (int nt = 0; nt < 2; ++nt) {
      f16x8 af = *(const f16x8*)(Wlf + (size_t)(nc0 + nt * 16 + lm) * HH + ks * 32 + lg * 8);
      acc[0][nt] = __builtin_amdgcn_mfma_f32_16x16x32_f16(af, bf0, acc[0][nt], 0, 0, 0);
      acc[1][nt] = __builtin_amdgcn_mfma_f32_16x16x32_f16(af, bf1, acc[1][nt], 0, 0, 0);
    }
  }
  float sum[2] = {0.f, 0.f}, sq[2] = {0.f, 0.f};
  f32x4 o[2][2];
#pragma unroll
  for (int g = 0; g < 2; ++g) {
    int row = rbase + g * 16 + lm;
#pragma unroll
    for (int nt = 0; nt < 2; ++nt) {
      int n = nc0 + nt * 16 + lg * 4;
      float4 rv = *(const float4*)(resid + (size_t)row * HH + n);
      float4 bv = *(const float4*)(bl + n);
      f32x4 v = acc[g][nt];
      v[0] += rv.x + bv.x; v[1] += rv.y + bv.y;
      v[2] += rv.z + bv.z; v[3] += rv.w + bv.w;
      o[g][nt] = v;
      sum[g] += v[0] + v[1] + v[2] + v[3];
      sq[g] += v[0] * v[0] + v[1] * v[1] + v[2] * v[2] + v[3] * v[3];
    }
    sum[g] += __shfl_xor(sum[g], 16); sum[g] += __shfl_xor(sum[g], 32);
    sq[g] += __shfl_xor(sq[g], 16);  sq[g] += __shfl_xor(sq[g], 32);
  }
  if (lane < 16) {
#pragma unroll
    for (int g = 0; g < 2; ++g) {
      red[wave][g * 16 + lm][0] = sum[g];
      red[wave][g * 16 + lm][1] = sq[g];
    }
  }
  __syncthreads();
#pragma unroll
  for (int g = 0; g < 2; ++g) {
    int lr = g * 16 + lm;
    float ts = red[0][lr][0] + red[1][lr][0] + red[2][lr][0] + red[3][lr][0];
    float tq = red[0][lr][1] + red[1][lr][1] + red[2][lr][1] + red[3][lr][1];
    float mean = ts * (1.0f / HH);
    float var = fmaxf((tq - (float)HH * mean * mean) * (1.0f / (HH - 1)), 0.0f);
    float inv = 1.0f / (sqrtf(var) + 1e-6f);
#pragma unroll
    for (int nt = 0; nt < 2; ++nt) {
      int n = nc0 + nt * 16 + lg * 4;
      float4 av = *(const float4*)(ln2a + n);
      float4 b2 = *(const float4*)(ln2b + n);
      f16x4 w;
      w[0] = (f16)(av.x * (o[g][nt][0] - mean) * inv + b2.x);
      w[1] = (f16)(av.y * (o[g][nt][1] - mean) * inv + b2.y);
      w[2] = (f16)(av.z * (o[g][nt][2] - mean) * inv + b2.z);
      w[3] = (f16)(av.w * (o[g][nt][3] - mean) * inv + b2.w);
      *(f16x4*)(&n2t[lr][n]) = w;
    }
  }
  __syncthreads();

  f32x4 fa[2][2] = {};
#pragma unroll
  for (int ks = 0; ks < 4; ++ks) {
    f16x8 bf0 = *(const f16x8*)(&n2t[lm][ks * 32 + lg * 8]);
    f16x8 bf1 = *(const f16x8*)(&n2t[16 + lm][ks * 32 + lg * 8]);
#pragma unroll
    for (int nt = 0; nt < 2; ++nt) {
      f16x8 af = *(const f16x8*)(W1f + (size_t)(nc0 + nt * 16 + lm) * HH + ks * 32 + lg * 8);
      fa[0][nt] = __builtin_amdgcn_mfma_f32_16x16x32_f16(af, bf0, fa[0][nt], 0, 0, 0);
      fa[1][nt] = __builtin_amdgcn_mfma_f32_16x16x32_f16(af, bf1, fa[1][nt], 0, 0, 0);
    }
  }
#pragma unroll
  for (int g = 0; g < 2; ++g) {
    int row = rbase + g * 16 + lm;
    float fs = fscale[row & (SS - 1)];
#pragma unroll
    for (int nt = 0; nt < 2; ++nt) {
      int n = nc0 + nt * 16 + lg * 4;
      float4 bv = *(const float4*)(b1 + n);
      const float* bp = &bv.x;
#pragma unroll
      for (int e = 0; e < 4; ++e) {
        float hf = fs * (fa[g][nt][e] + bp[e]);
        float u = 0.7978845608028654f * hf * (1.0f + 0.044715f * hf * hf);
        float ex = __builtin_amdgcn_exp2f(u * 2.8853900817779268f);  // exp(2u)
        float t = 1.0f - 2.0f / (ex + 1.0f);
        o[g][nt][e] += 0.5f * hf * (1.0f + t);
      }
      *(f32x4*)(out + (size_t)row * HH + n) = o[g][nt];
    }
  }
}

extern "C" void kernel_launch(void* const* d_in, const int* in_sizes, int n_in,
                              void* d_out, int out_size, void* d_ws, size_t ws_size,
                              hipStream_t stream) {
  const float* hidden = (const float*)d_in[0];
  const int* mask = (const int*)d_in[1];
  const float* scalew = (const float*)d_in[2];
  const float* Wl = (const float*)d_in[3];
  const float* bl = (const float*)d_in[4];
  const float* W1 = (const float*)d_in[5];
  const float* b1 = (const float*)d_in[6];
  const float* fscale = (const float*)d_in[7];
  const float* ln1a = (const float*)d_in[8];
  const float* ln1b = (const float*)d_in[9];
  const float* ln2a = (const float*)d_in[10];
  const float* ln2b = (const float*)d_in[11];
  float* out = (float*)d_out;

  const size_t NE = (size_t)BB * SS * HH;  // 2M elements
  f16* n1 = (f16*)d_ws;
  f16* hattf = n1 + NE;
  f16* Wlf = hattf + NE;
  f16* W1f = Wlf + HH * HH;
  int* idx = (int*)(W1f + HH * HH);
  int* nkcnt = idx + BB * SS;
  int* nkpad = nkcnt + BB;

  stage1_kernel<<<1064, 256, 0, stream>>>(hidden, ln1a, ln1b, Wl, W1, mask,
                                          n1, Wlf, W1f, idx, nkcnt, nkpad);
  attn_kernel<<<BB * NHH * (SS / 128), 256, 0, stream>>>(n1, idx, nkcnt, nkpad,
                                                         scalew, hattf);
  mlp_kernel<<<BB * SS / 32, 256, 0, stream>>>(hattf, Wlf, bl, hidden, ln2a, ln2b,
                                               W1f, b1, fscale, out);
}

// Round 9
// 45.488 us; speedup vs baseline: 2.8433x; 1.0095x over previous
//
#include <hip/hip_runtime.h>

#define BB 8
#define SS 2048
#define HH 128
#define NHH 4
#define DHH 32

typedef _Float16 f16;
typedef f16 f16x4 __attribute__((ext_vector_type(4)));
typedef f16 f16x8 __attribute__((ext_vector_type(8)));
typedef float f32x4 __attribute__((ext_vector_type(4)));

#define BIAS0 -5.7707801636f  /* (-4)*log2e */

__device__ __forceinline__ f16x8 cat(f16x4 a, f16x4 b) {
  return (f16x8){a[0], a[1], a[2], a[3], b[0], b[1], b[2], b[3]};
}

// hardware transpose read (R2/R3/R5-proven): on a contiguous [16 rows][16 cols]
// f16 panel, tr_read(panel + lane*4) gives lane(lg,lm) elem j = panel[4*lg+j][lm].
// CALLER MUST wait lgkmcnt(0) + sched_barrier(0) before use (rule #18).
// tr_reads must be issued BEFORE any compiler-emitted ds_read whose wait should
// cover them (in-order DS completion makes compiler lgkmcnt(N) waits safe).
__device__ __forceinline__ f16x4 tr_read(const f16* p) {
  f16x4 d;
  asm volatile("ds_read_b64_tr_b16 %0, %1"
               : "=v"(d)
               : "v"((__attribute__((address_space(3))) const f16*)p)
               : "memory");
  return d;
}

// ---- stage1: LN1 (blocks 0..1023) + weights->f16 (1024..1055) + mask scan (1056..1063)
__global__ __launch_bounds__(256) void stage1_kernel(const float* __restrict__ x,
                                                     const float* __restrict__ ga,
                                                     const float* __restrict__ gb,
                                                     const float* __restrict__ Wl,
                                                     const float* __restrict__ W1,
                                                     const int* __restrict__ mask,
                                                     f16* __restrict__ n1,
                                                     f16* __restrict__ Wlf,
                                                     f16* __restrict__ W1f,
                                                     int* __restrict__ idx,
                                                     int* __restrict__ nkcnt,
                                                     int* __restrict__ nkpad) {
  const int tid = threadIdx.x;
  if (blockIdx.x < 1024) {  // ---- LayerNorm path: 16 rows/block
    const int wave = tid >> 6, lane = tid & 63;
    const int grp = lane >> 4, lm = lane & 15;
    const int r = wave * 4 + grp;
    const size_t row = (size_t)blockIdx.x * 16 + r;

    const float* xr = x + row * HH + lm * 8;
    float4 v0 = *(const float4*)(xr);
    float4 v1 = *(const float4*)(xr + 4);
    float xv[8] = {v0.x, v0.y, v0.z, v0.w, v1.x, v1.y, v1.z, v1.w};
    float sum = 0.f, sq = 0.f;
#pragma unroll
    for (int j = 0; j < 8; ++j) { sum += xv[j]; sq += xv[j] * xv[j]; }
#pragma unroll
    for (int m = 1; m < 16; m <<= 1) {
      sum += __shfl_xor(sum, m);
      sq += __shfl_xor(sq, m);
    }
    float mean = sum * (1.0f / HH);
    float var = fmaxf((sq - (float)HH * mean * mean) * (1.0f / (HH - 1)), 0.0f);
    float inv = 1.0f / (sqrtf(var) + 1e-6f);

    float4 a0 = *(const float4*)(ga + lm * 8);
    float4 a1 = *(const float4*)(ga + lm * 8 + 4);
    float4 b0 = *(const float4*)(gb + lm * 8);
    float4 b1 = *(const float4*)(gb + lm * 8 + 4);
    float av[8] = {a0.x, a0.y, a0.z, a0.w, a1.x, a1.y, a1.z, a1.w};
    float bv[8] = {b0.x, b0.y, b0.z, b0.w, b1.x, b1.y, b1.z, b1.w};
    f16x8 w;
#pragma unroll
    for (int j = 0; j < 8; ++j) w[j] = (f16)(av[j] * (xv[j] - mean) * inv + bv[j]);
    *(f16x8*)(n1 + row * HH + lm * 8) = w;
    return;
  }
  if (blockIdx.x < 1056) {  // ---- weight conversion path
    int g = (blockIdx.x - 1024) * 256 + tid;
    if (g < 4096) {
      float4 w = ((const float4*)Wl)[g];
      f16x4 o = {(f16)w.x, (f16)w.y, (f16)w.z, (f16)w.w};
      ((f16x4*)Wlf)[g] = o;
    } else {
      float4 w = ((const float4*)W1)[g - 4096];
      f16x4 o = {(f16)w.x, (f16)w.y, (f16)w.z, (f16)w.w};
      ((f16x4*)W1f)[g - 4096] = o;
    }
    return;
  }
  // ---- mask scan path: one block per batch
  const int b = blockIdx.x - 1056;
  __shared__ int ps[256];
  int m8[8];
  int cnt = 0;
  const int* mp = mask + b * SS + tid * 8;
#pragma unroll
  for (int j = 0; j < 8; ++j) {
    m8[j] = mp[j];
    cnt += (m8[j] != 0);
  }
  ps[tid] = cnt;
  __syncthreads();
  for (int off = 1; off < 256; off <<= 1) {
    int v = (tid >= off) ? ps[tid - off] : 0;
    __syncthreads();
    ps[tid] += v;
    __syncthreads();
  }
  int pos = ps[tid] - cnt;  // exclusive prefix
#pragma unroll
  for (int j = 0; j < 8; ++j) {
    if (m8[j] != 0) idx[b * SS + pos++] = tid * 8 + j;
  }
  __syncthreads();
  int nkv = ps[255];
  int npv = (nkv + 63) & ~63;
  if (npv == 0) npv = 64;
  for (int jj = nkv + tid; jj < npv; jj += 256) idx[b * SS + jj] = 0;  // safe pad rows
  if (tid == 255) { nkcnt[b] = nkv; nkpad[b] = npv; }
}

// ---- attention: self-gathering, K-tile doubles as V via tr_read, 64 q/wave ---
// grid = B*NH*(S/256) = 256; block 256 = 4 waves; chunk = 64 compacted keys
__global__ __launch_bounds__(256, 1) void attn_kernel(const f16* __restrict__ n1,
                                                      const int* __restrict__ idx,
                                                      const int* __restrict__ nkcnt,
                                                      const int* __restrict__ nkpad,
                                                      const float* __restrict__ scalew,
                                                      f16* __restrict__ hatt) {
  const int tid = threadIdx.x;
  const int qb = blockIdx.x & 7;
  const int h = (blockIdx.x >> 3) & 3;
  const int b = blockIdx.x >> 5;
  const int wave = tid >> 6, lane = tid & 63;
  const int lg = lane >> 4, lm = lane & 15;
  const int nk = nkcnt[b];
  const int ns = nkpad[b] >> 6;

  __shared__ __align__(16) f16 Kt[2][2][64][16];  // [buf][dgroup][key][16d]
  __shared__ __align__(16) int idxL[SS];          // 8 KB compacted-index cache

  const f16* __restrict__ nb = n1 + (size_t)b * SS * HH + h * DHH;

  const int np = ns << 6;
  for (int j = tid * 4; j < np; j += 1024)
    *(int4*)&idxL[j] = *(const int4*)(idx + b * SS + j);

  const int q0 = qb * 256 + wave * 64 + lm;
  f16x8 qf[4];
  float sc2[4];
#pragma unroll
  for (int qt = 0; qt < 4; ++qt) {
    int q = q0 + qt * 16;
    qf[qt] = *(const f16x8*)(nb + (size_t)q * HH + lg * 8);
    sc2[qt] = scalew[h * SS + q] * 0.2550680718664f;  // (1/sqrt32)*log2e
  }

  const int sk = tid >> 2, sp = tid & 3;  // staging: key sk, 16B part sp

  const f32x4 zero = {0.f, 0.f, 0.f, 0.f};
  f32x4 acc[4][2] = {{zero, zero}, {zero, zero}, {zero, zero}, {zero, zero}};
  f32x4 lacc[4] = {zero, zero, zero, zero};
  const f16x8 ones = {(f16)1, (f16)1, (f16)1, (f16)1, (f16)1, (f16)1, (f16)1, (f16)1};

  __syncthreads();  // idxL ready
  {
    int row = idxL[sk];
    f16x8 kreg = *(const f16x8*)(nb + (size_t)row * HH + sp * 8);
    *(f16x8*)(&Kt[0][sp >> 1][sk][(sp & 1) * 8]) = kreg;
  }
  __syncthreads();

  for (int c = 0; c < ns; ++c) {
    const int buf = c & 1;
    const int k0 = c * 64;
    f16x8 kreg;
    if (c + 1 < ns) {  // issue next chunk's gather early
      int row = idxL[k0 + 64 + sk];
      kreg = *(const f16x8*)(nb + (size_t)row * HH + sp * 8);
    }
    // V^T fragments first (in-order DS completion keeps compiler kf waits safe)
    f16x4 t0a = tr_read(&Kt[buf][0][0][0] + lane * 4);   // dh0 keys 0-15
    f16x4 t0b = tr_read(&Kt[buf][0][16][0] + lane * 4);  // dh0 keys 16-31
    f16x4 t0c = tr_read(&Kt[buf][0][32][0] + lane * 4);
    f16x4 t0d = tr_read(&Kt[buf][0][48][0] + lane * 4);
    f16x4 t1a = tr_read(&Kt[buf][1][0][0] + lane * 4);   // dh1
    f16x4 t1b = tr_read(&Kt[buf][1][16][0] + lane * 4);
    f16x4 t1c = tr_read(&Kt[buf][1][32][0] + lane * 4);
    f16x4 t1d = tr_read(&Kt[buf][1][48][0] + lane * 4);

    f16x8 kf[4];
#pragma unroll
    for (int t = 0; t < 4; ++t)
      kf[t] = *(const f16x8*)(&Kt[buf][lg >> 1][t * 16 + lm][(lg & 1) * 8]);

    const bool tail = (k0 + 64 > nk);
    f16x8 pf[4][2];
#define PF_LOOP(MASKED)                                                                   \
  _Pragma("unroll") for (int qt = 0; qt < 4; ++qt) {                                      \
    _Pragma("unroll") for (int t = 0; t < 4; ++t) {                                       \
      f32x4 st = __builtin_amdgcn_mfma_f32_16x16x32_f16(kf[t], qf[qt], zero, 0, 0, 0);    \
      _Pragma("unroll") for (int r = 0; r < 4; ++r) {                                     \
        float pe = __builtin_amdgcn_exp2f(st[r] * sc2[qt] + BIAS0);                       \
        if (MASKED && (k0 + t * 16 + lg * 4 + r >= nk)) pe = 0.0f;                        \
        pf[qt][t >> 1][(t & 1) * 4 + r] = (f16)pe;                                        \
      }                                                                                   \
    }                                                                                     \
  }
    if (!tail) { PF_LOOP(false) } else { PF_LOOP(true) }
#undef PF_LOOP

    // denominator on matrix pipe
#pragma unroll
    for (int qt = 0; qt < 4; ++qt) {
#pragma unroll
      for (int s = 0; s < 2; ++s)
        lacc[qt] = __builtin_amdgcn_mfma_f32_16x16x32_f16(ones, pf[qt][s], lacc[qt], 0, 0, 0);
    }

    asm volatile("s_waitcnt lgkmcnt(0)" ::: "memory");
    __builtin_amdgcn_sched_barrier(0);

    f16x8 vf;
    vf = cat(t0a, t0b);  // dh0, keys 0-31
#pragma unroll
    for (int qt = 0; qt < 4; ++qt)
      acc[qt][0] = __builtin_amdgcn_mfma_f32_16x16x32_f16(vf, pf[qt][0], acc[qt][0], 0, 0, 0);
    vf = cat(t1a, t1b);  // dh1, keys 0-31
#pragma unroll
    for (int qt = 0; qt < 4; ++qt)
      acc[qt][1] = __builtin_amdgcn_mfma_f32_16x16x32_f16(vf, pf[qt][0], acc[qt][1], 0, 0, 0);
    vf = cat(t0c, t0d);  // dh0, keys 32-63
#pragma unroll
    for (int qt = 0; qt < 4; ++qt)
      acc[qt][0] = __builtin_amdgcn_mfma_f32_16x16x32_f16(vf, pf[qt][1], acc[qt][0], 0, 0, 0);
    vf = cat(t1c, t1d);  // dh1, keys 32-63
#pragma unroll
    for (int qt = 0; qt < 4; ++qt)
      acc[qt][1] = __builtin_amdgcn_mfma_f32_16x16x32_f16(vf, pf[qt][1], acc[qt][1], 0, 0, 0);

    if (c + 1 < ns)
      *(f16x8*)(&Kt[buf ^ 1][sp >> 1][sk][(sp & 1) * 8]) = kreg;
    __syncthreads();
  }

#pragma unroll
  for (int qt = 0; qt < 4; ++qt) {
    float inv = 1.0f / lacc[qt][0];
    int q = q0 + qt * 16;
    f16* op = hatt + (size_t)(b * SS + q) * HH + h * DHH;
    f16x4 o0 = {(f16)(acc[qt][0][0] * inv), (f16)(acc[qt][0][1] * inv),
                (f16)(acc[qt][0][2] * inv), (f16)(acc[qt][0][3] * inv)};
    f16x4 o1 = {(f16)(acc[qt][1][0] * inv), (f16)(acc[qt][1][1] * inv),
                (f16)(acc[qt][1][2] * inv), (f16)(acc[qt][1][3] * inv)};
    *(f16x4*)(op + lg * 4) = o0;
    *(f16x4*)(op + 16 + lg * 4) = o1;
  }
}

// ------- fused MLP: 32 rows/block, 256 thr (4 waves x 32 cols) ---------------
__global__ __launch_bounds__(256) void mlp_kernel(const f16* __restrict__ X,
                                                  const f16* __restrict__ Wlf,
                                                  const float* __restrict__ bl,
                                                  const float* __restrict__ resid,
                                                  const float* __restrict__ ln2a,
                                                  const float* __restrict__ ln2b,
                                                  const f16* __restrict__ W1f,
                                                  const float* __restrict__ b1,
                                                  const float* __restrict__ fscale,
                                                  float* __restrict__ out) {
  const int tid = threadIdx.x;
  const int wave = tid >> 6, lane = tid & 63;
  const int lg = lane >> 4, lm = lane & 15;
  const int rbase = blockIdx.x * 32;
  const int nc0 = wave * 32;

  __shared__ __align__(16) f16 n2t[32][136];
  __shared__ float red[4][32][2];

  f32x4 acc[2][2] = {};
  const f16* xr0 = X + (size_t)(rbase + lm) * HH;
  const f16* xr1 = X + (size_t)(rbase + 16 + lm) * HH;
#pragma unroll
  for (int ks = 0; ks < 4; ++ks) {
    f16x8 bf0 = *(const f16x8*)(xr0 + ks * 32 + lg * 8);
    f16x8 bf1 = *(const f16x8*)(xr1 + ks * 32 + lg * 8);
#pragma unroll
    for (int nt = 0; nt < 2; ++nt) {
      f16x8 af = *(const f16x8*)(Wlf + (size_t)(nc0 + nt * 16 + lm) * HH + ks * 32 + lg * 8);
      acc[0][nt] = __builtin_amdgcn_mfma_f32_16x16x32_f16(af, bf0, acc[0][nt], 0, 0, 0);
      acc[1][nt] = __builtin_amdgcn_mfma_f32_16x16x32_f16(af, bf1, acc[1][nt], 0, 0, 0);
    }
  }
  float sum[2] = {0.f, 0.f}, sq[2] = {0.f, 0.f};
  f32x4 o[2][2];
#pragma unroll
  for (int g = 0; g < 2; ++g) {
    int row = rbase + g * 16 + lm;
#pragma unroll
    for (int nt = 0; nt < 2; ++nt) {
      int n = nc0 + nt * 16 + lg * 4;
      float4 rv = *(const float4*)(resid + (size_t)row * HH + n);
      float4 bv = *(const float4*)(bl + n);
      f32x4 v = acc[g][nt];
      v[0] += rv.x + bv.x; v[1] += rv.y + bv.y;
      v[2] += rv.z + bv.z; v[3] += rv.w + bv.w;
      o[g][nt] = v;
      sum[g] += v[0] + v[1] + v[2] + v[3];
      sq[g] += v[0] * v[0] + v[1] * v[1] + v[2] * v[2] + v[3] * v[3];
    }
    sum[g] += __shfl_xor(sum[g], 16); sum[g] += __shfl_xor(sum[g], 32);
    sq[g] += __shfl_xor(sq[g], 16);  sq[g] += __shfl_xor(sq[g], 32);
  }
  if (lane < 16) {
#pragma unroll
    for (int g = 0; g < 2; ++g) {
      red[wave][g * 16 + lm][0] = sum[g];
      red[wave][g * 16 + lm][1] = sq[g];
    }
  }
  __syncthreads();
#pragma unroll
  for (int g = 0; g < 2; ++g) {
    int lr = g * 16 + lm;
    float ts = red[0][lr][0] + red[1][lr][0] + red[2][lr][0] + red[3][lr][0];
    float tq = red[0][lr][1] + red[1][lr][1] + red[2][lr][1] + red[3][lr][1];
    float mean = ts * (1.0f / HH);
    float var = fmaxf((tq - (float)HH * mean * mean) * (1.0f / (HH - 1)), 0.0f);
    float inv = 1.0f / (sqrtf(var) + 1e-6f);
#pragma unroll
    for (int nt = 0; nt < 2; ++nt) {
      int n = nc0 + nt * 16 + lg * 4;
      float4 av = *(const float4*)(ln2a + n);
      float4 b2 = *(const float4*)(ln2b + n);
      f16x4 w;
      w[0] = (f16)(av.x * (o[g][nt][0] - mean) * inv + b2.x);
      w[1] = (f16)(av.y * (o[g][nt][1] - mean) * inv + b2.y);
      w[2] = (f16)(av.z * (o[g][nt][2] - mean) * inv + b2.z);
      w[3] = (f16)(av.w * (o[g][nt][3] - mean) * inv + b2.w);
      *(f16x4*)(&n2t[lr][n]) = w;
    }
  }
  __syncthreads();

  f32x4 fa[2][2] = {};
#pragma unroll
  for (int ks = 0; ks < 4; ++ks) {
    f16x8 bf0 = *(const f16x8*)(&n2t[lm][ks * 32 + lg * 8]);
    f16x8 bf1 = *(const f16x8*)(&n2t[16 + lm][ks * 32 + lg * 8]);
#pragma unroll
    for (int nt = 0; nt < 2; ++nt) {
      f16x8 af = *(const f16x8*)(W1f + (size_t)(nc0 + nt * 16 + lm) * HH + ks * 32 + lg * 8);
      fa[0][nt] = __builtin_amdgcn_mfma_f32_16x16x32_f16(af, bf0, fa[0][nt], 0, 0, 0);
      fa[1][nt] = __builtin_amdgcn_mfma_f32_16x16x32_f16(af, bf1, fa[1][nt], 0, 0, 0);
    }
  }
#pragma unroll
  for (int g = 0; g < 2; ++g) {
    int row = rbase + g * 16 + lm;
    float fs = fscale[row & (SS - 1)];
#pragma unroll
    for (int nt = 0; nt < 2; ++nt) {
      int n = nc0 + nt * 16 + lg * 4;
      float4 bv = *(const float4*)(b1 + n);
      const float* bp = &bv.x;
#pragma unroll
      for (int e = 0; e < 4; ++e) {
        float hf = fs * (fa[g][nt][e] + bp[e]);
        float u = 0.7978845608028654f * hf * (1.0f + 0.044715f * hf * hf);
        float ex = __builtin_amdgcn_exp2f(u * 2.8853900817779268f);  // exp(2u)
        float t = 1.0f - 2.0f / (ex + 1.0f);
        o[g][nt][e] += 0.5f * hf * (1.0f + t);
      }
      *(f32x4*)(out + (size_t)row * HH + n) = o[g][nt];
    }
  }
}

extern "C" void kernel_launch(void* const* d_in, const int* in_sizes, int n_in,
                              void* d_out, int out_size, void* d_ws, size_t ws_size,
                              hipStream_t stream) {
  const float* hidden = (const float*)d_in[0];
  const int* mask = (const int*)d_in[1];
  const float* scalew = (const float*)d_in[2];
  const float* Wl = (const float*)d_in[3];
  const float* bl = (const float*)d_in[4];
  const float* W1 = (const float*)d_in[5];
  const float* b1 = (const float*)d_in[6];
  const float* fscale = (const float*)d_in[7];
  const float* ln1a = (const float*)d_in[8];
  const float* ln1b = (const float*)d_in[9];
  const float* ln2a = (const float*)d_in[10];
  const float* ln2b = (const float*)d_in[11];
  float* out = (float*)d_out;

  const size_t NE = (size_t)BB * SS * HH;  // 2M elements
  f16* n1 = (f16*)d_ws;
  f16* hattf = n1 + NE;
  f16* Wlf = hattf + NE;
  f16* W1f = Wlf + HH * HH;
  int* idx = (int*)(W1f + HH * HH);
  int* nkcnt = idx + BB * SS;
  int* nkpad = nkcnt + BB;

  stage1_kernel<<<1064, 256, 0, stream>>>(hidden, ln1a, ln1b, Wl, W1, mask,
                                          n1, Wlf, W1f, idx, nkcnt, nkpad);
  attn_kernel<<<BB * NHH * (SS / 256), 256, 0, stream>>>(n1, idx, nkcnt, nkpad,
                                                         scalew, hattf);
  mlp_kernel<<<BB * SS / 32, 256, 0, stream>>>(hattf, Wlf, bl, hidden, ln2a, ln2b,
                                               W1f, b1, fscale, out);
}